// Round 14
// baseline (124.287 us; speedup 1.0000x reference)
//
#include <hip/hip_runtime.h>
#include <hip/hip_fp16.h>

#define TPB     256
#define BSH     9              // bucket = dst >> 9  (512 nodes / bucket)
#define BW      512
#define EPB     2048           // edges per partition block (fused kernel)
#define NBMAX   256            // max buckets (n_nodes <= 131072)
#define S_SPLIT 8              // edge-slices per bucket in k_red
#define FXS     2097152.0f     // 2^21 fixed-point scale
#define FXSI    (1.0f / 2097152.0f)

static __device__ __forceinline__ float sigmoidf(float v) {
    return __builtin_amdgcn_rcpf(1.0f + __expf(-v));
}

// unpack 8 halves (one uint4) to 8 floats
static __device__ __forceinline__ void unpack8(uint4 u, float o[8]) {
    union { unsigned int u; __half2 h; } c0, c1, c2, c3;
    c0.u = u.x; c1.u = u.y; c2.u = u.z; c3.u = u.w;
    float2 f0 = __half22float2(c0.h), f1 = __half22float2(c1.h);
    float2 f2 = __half22float2(c2.h), f3 = __half22float2(c3.h);
    o[0]=f0.x; o[1]=f0.y; o[2]=f1.x; o[3]=f1.y;
    o[4]=f2.x; o[5]=f2.y; o[6]=f3.x; o[7]=f3.y;
}

// ===========================================================================
// K1: per-node precompute (fp16 exp-form, round-11-validated):
//   egih[n] = exp(-(f@(W1a-W1b)+b1)),  egjh[n] = exp(-(f@W1b))
//   layer-1 sigmoid per edge = rcp(1 + ei*ej): no exp in L1.
// ===========================================================================
__global__ void k_feat(const float* __restrict__ x,
                       const float* __restrict__ W_in,
                       const float* __restrict__ b_in,
                       const float* __restrict__ W1,
                       const float* __restrict__ b1,
                       __half* __restrict__ egih,
                       __half* __restrict__ egjh, int n_nodes) {
    int n = blockIdx.x * blockDim.x + threadIdx.x;
    if (n >= n_nodes) return;
    float x0 = x[3*n], x1 = x[3*n+1], x2 = x[3*n+2];
    float f[11];
#pragma unroll
    for (int c = 0; c < 8; ++c)
        f[c] = tanhf(b_in[c] + x0*W_in[c] + x1*W_in[8+c] + x2*W_in[16+c]);
    f[8] = x0; f[9] = x1; f[10] = x2;
    __align__(16) __half hi[8], hj[8];
#pragma unroll
    for (int h = 0; h < 8; ++h) {
        float vi = b1[h], vj = 0.0f;
#pragma unroll
        for (int k = 0; k < 11; ++k) {
            float wa = W1[k*8+h], wb = W1[(11+k)*8+h];
            vi += f[k] * (wa - wb);
            vj += f[k] * wb;
        }
        hi[h] = __float2half_rn(__expf(-vi));
        hj[h] = __float2half_rn(__expf(-vj));
    }
    *(uint4*)(egih + (size_t)n * 8) = *(const uint4*)hi;
    *(uint4*)(egjh + (size_t)n * 8) = *(const uint4*)hj;
}

// ===========================================================================
// K2: per-block bucket histogram -> raw counts
// ===========================================================================
__global__ void k_hist2(const int* __restrict__ dst, int* __restrict__ raw,
                        int n_edges, int NB) {
    __shared__ int cnt[NBMAX];
    for (int b = threadIdx.x; b < NB; b += blockDim.x) cnt[b] = 0;
    __syncthreads();
    int e0 = blockIdx.x * EPB;
#pragma unroll
    for (int k = 0; k < EPB / (TPB * 4); ++k) {
        int e = e0 + k * TPB * 4 + threadIdx.x * 4;
        if (e + 3 < n_edges) {
            int4 d4 = *(const int4*)(dst + e);
            atomicAdd(&cnt[d4.x >> BSH], 1);
            atomicAdd(&cnt[d4.y >> BSH], 1);
            atomicAdd(&cnt[d4.z >> BSH], 1);
            atomicAdd(&cnt[d4.w >> BSH], 1);
        } else {
            int qe = min(e + 4, n_edges);
            for (int q = e; q < qe; ++q)
                atomicAdd(&cnt[dst[q] >> BSH], 1);
        }
    }
    __syncthreads();
    for (int b = threadIdx.x; b < NB; b += blockDim.x)
        raw[(size_t)blockIdx.x * NB + b] = cnt[b];
}

// ===========================================================================
// K3: per-bucket (column) exclusive scan over blocks: raw -> rel, totals
// ===========================================================================
__global__ void k_scan_cols(const int* __restrict__ raw, int* __restrict__ rel,
                            int* __restrict__ totals, int NB, int NBLK) {
    __shared__ int s[TPB];
    int b = blockIdx.x, t = threadIdx.x;
    int carry = 0;
    for (int q = 0; q < NBLK; q += TPB) {
        int blk = q + t;
        int v = (blk < NBLK) ? raw[(size_t)blk * NB + b] : 0;
        __syncthreads();
        s[t] = v; __syncthreads();
        for (int o = 1; o < TPB; o <<= 1) {
            int u = (t >= o) ? s[t - o] : 0;
            __syncthreads();
            s[t] += u;
            __syncthreads();
        }
        if (blk < NBLK) rel[(size_t)blk * NB + b] = carry + s[t] - v;
        carry += s[TPB - 1];
    }
    if (t == 0) totals[b] = carry;
}

// K3b: exclusive scan of 4-padded totals -> base
__global__ void k_base(const int* __restrict__ totals, int* __restrict__ base,
                       int NB) {
    __shared__ int s[NBMAX];
    int t = threadIdx.x;
    int v = (t < NB) ? ((totals[t] + 3) & ~3) : 0;
    s[t] = v; __syncthreads();
    for (int o = 1; o < NBMAX; o <<= 1) {
        int u = (t >= o) ? s[t - o] : 0;
        __syncthreads();
        s[t] += u;
        __syncthreads();
    }
    if (t < NB) base[t] = s[t] - v;
}

// ===========================================================================
// K4 (FUSED): per-edge MLP in original order + quantize + LDS-staged scatter.
//   Streams src/dst (int4), gathers egjh[src], egih[dst] (16B fp16, L2-hot),
//   computes (pa,pc), quantizes to int, places (int2, dl) in LDS stage via
//   cursor atomics, then writes bucket runs out coalesced.
// ===========================================================================
__launch_bounds__(TPB)
__global__ void k_fused(const int* __restrict__ src, const int* __restrict__ dst,
                        const __half* __restrict__ egih, const __half* __restrict__ egjh,
                        const float* __restrict__ W2, const float* __restrict__ b2,
                        const float* __restrict__ W_e,
                        const int* __restrict__ raw, const int* __restrict__ rel,
                        const int* __restrict__ base,
                        int2* __restrict__ papc_s, unsigned short* __restrict__ dls,
                        int n_edges, int NB) {
    __shared__ int2 stp[EPB];            // 16 KB quantized (pa,pc)
    __shared__ unsigned short sdl[EPB];  // 4 KB dst-local
    __shared__ int cnt[NBMAX], lscan[NBMAX], gd[NBMAX];
    __shared__ int s[TPB];
    int t = threadIdx.x;

    // local exclusive scan of this block's raw counts (NB <= 256: one chunk)
    {
        int v = (t < NB) ? raw[(size_t)blockIdx.x * NB + t] : 0;
        s[t] = v; __syncthreads();
        for (int o = 1; o < TPB; o <<= 1) {
            int u = (t >= o) ? s[t - o] : 0;
            __syncthreads();
            s[t] += u;
            __syncthreads();
        }
        if (t < NB) {
            lscan[t] = s[t] - v;
            cnt[t]   = s[t] - v;
            gd[t]    = base[t] + rel[(size_t)blockIdx.x * NB + t];
        }
    }
    __syncthreads();

    int e0 = blockIdx.x * EPB;
#pragma unroll
    for (int k = 0; k < EPB / (TPB * 4); ++k) {
        int e = e0 + k * TPB * 4 + t * 4;
        if (e + 3 < n_edges) {
            int4 s4 = *(const int4*)(src + e);
            int4 d4 = *(const int4*)(dst + e);
            uint4 uj0 = *(const uint4*)(egjh + (size_t)s4.x * 8);
            uint4 uj1 = *(const uint4*)(egjh + (size_t)s4.y * 8);
            uint4 uj2 = *(const uint4*)(egjh + (size_t)s4.z * 8);
            uint4 uj3 = *(const uint4*)(egjh + (size_t)s4.w * 8);
            uint4 ui0 = *(const uint4*)(egih + (size_t)d4.x * 8);
            uint4 ui1 = *(const uint4*)(egih + (size_t)d4.y * 8);
            uint4 ui2 = *(const uint4*)(egih + (size_t)d4.z * 8);
            uint4 ui3 = *(const uint4*)(egih + (size_t)d4.w * 8);
            float ej[4][8], ei[4][8];
            unpack8(uj0, ej[0]); unpack8(uj1, ej[1]);
            unpack8(uj2, ej[2]); unpack8(uj3, ej[3]);
            unpack8(ui0, ei[0]); unpack8(ui1, ei[1]);
            unpack8(ui2, ei[2]); unpack8(ui3, ei[3]);
            float m[4][8];
#pragma unroll
            for (int q = 0; q < 4; ++q)
#pragma unroll
                for (int kk = 0; kk < 8; ++kk)
                    m[q][kk] = __builtin_amdgcn_rcpf(1.0f + ei[q][kk] * ej[q][kk]);
            float pa[4] = {0,0,0,0}, pc[4] = {0,0,0,0};
#pragma unroll
            for (int h = 0; h < 8; ++h) {
                float bb = b2[h];
                float v[4] = {bb, bb, bb, bb};
#pragma unroll
                for (int kk = 0; kk < 8; ++kk) {
                    float w = W2[kk*8+h];
#pragma unroll
                    for (int q = 0; q < 4; ++q) v[q] += m[q][kk] * w;
                }
                float wa = W_e[h], wc = W_e[11+h];
#pragma unroll
                for (int q = 0; q < 4; ++q) {
                    float z = sigmoidf(v[q]);
                    pa[q] += z * wa; pc[q] += z * wc;
                }
            }
            int dd[4] = { d4.x, d4.y, d4.z, d4.w };
#pragma unroll
            for (int q = 0; q < 4; ++q) {
                int p = atomicAdd(&cnt[dd[q] >> BSH], 1);
                stp[p] = make_int2(__float2int_rn(pa[q] * FXS),
                                   __float2int_rn(pc[q] * FXS));
                sdl[p] = (unsigned short)(dd[q] & (BW - 1));
            }
        } else {
            int qe = min(e + 4, n_edges);
            for (int q = e; q < qe; ++q) {
                int sj = src[q], di = dst[q];
                float ej[8], ei[8];
                unpack8(*(const uint4*)(egjh + (size_t)sj * 8), ej);
                unpack8(*(const uint4*)(egih + (size_t)di * 8), ei);
                float m[8];
#pragma unroll
                for (int kk = 0; kk < 8; ++kk)
                    m[kk] = __builtin_amdgcn_rcpf(1.0f + ei[kk] * ej[kk]);
                float pa = 0, pc = 0;
#pragma unroll
                for (int h = 0; h < 8; ++h) {
                    float v = b2[h];
#pragma unroll
                    for (int kk = 0; kk < 8; ++kk) v += m[kk] * W2[kk*8+h];
                    float z = sigmoidf(v);
                    pa += z * W_e[h]; pc += z * W_e[11+h];
                }
                int p = atomicAdd(&cnt[di >> BSH], 1);
                stp[p] = make_int2(__float2int_rn(pa * FXS),
                                   __float2int_rn(pc * FXS));
                sdl[p] = (unsigned short)(di & (BW - 1));
            }
        }
    }
    __syncthreads();

    // coalesced run write-out, one wave per bucket
    int wid = t >> 6, lane = t & 63;
    for (int b = wid; b < NB; b += (TPB / 64)) {
        int ls = lscan[b];
        int le = cnt[b];
        int g0 = gd[b];
        for (int i = ls + lane; i < le; i += 64) {
            papc_s[g0 + (i - ls)] = stp[i];
            dls[g0 + (i - ls)]    = sdl[i];
        }
    }
}

// ===========================================================================
// K5: per-bucket-slice reduction — pure streaming + native ds_add_u32.
//   part stays int (exact); converted once in k_acc.
// ===========================================================================
__launch_bounds__(TPB)
__global__ void k_red(const unsigned short* __restrict__ dls,
                      const int2* __restrict__ papc_s,
                      const int* __restrict__ base, const int* __restrict__ totals,
                      int* __restrict__ part, int NB, int NBP) {
    __shared__ int sa[BW], sc[BW];   // 4 KB
    int t = threadIdx.x;
    int sl = blockIdx.x / NBP;
    int b  = blockIdx.x - sl * NBP;
    if (b >= NB) return;
    for (int i = t; i < BW; i += TPB) { sa[i] = 0; sc[i] = 0; }
    __syncthreads();

    int beg = base[b];
    int len = totals[b];
    int qs = (((len + S_SPLIT - 1) / S_SPLIT) + 3) & ~3;
    int s0 = beg + sl * qs;
    int s1 = min(beg + len, s0 + qs);

    for (int g = s0 + t * 4; g < s1; g += TPB * 4) {
        if (g + 4 <= s1) {
            ushort4 d4 = *(const ushort4*)(dls + g);
            const int4* pp = (const int4*)(papc_s + g);
            int4 q0 = pp[0], q1 = pp[1];
            atomicAdd(&sa[d4.x], q0.x); atomicAdd(&sc[d4.x], q0.y);
            atomicAdd(&sa[d4.y], q0.z); atomicAdd(&sc[d4.y], q0.w);
            atomicAdd(&sa[d4.z], q1.x); atomicAdd(&sc[d4.z], q1.y);
            atomicAdd(&sa[d4.w], q1.z); atomicAdd(&sc[d4.w], q1.w);
        } else {
            for (int e = g; e < s1; ++e) {
                int2 q = papc_s[e];
                int dl = dls[e];
                atomicAdd(&sa[dl], q.x); atomicAdd(&sc[dl], q.y);
            }
        }
    }
    __syncthreads();
    size_t row = (size_t)blockIdx.x * (2 * BW);
    for (int i = t; i < BW; i += TPB) {
        part[row + i]      = sa[i];
        part[row + BW + i] = sc[i];
    }
}

// ===========================================================================
// K6: reduce S_SPLIT int partials (exact) + x-projection -> ac[2n], ac[2n+1]
// ===========================================================================
__global__ void k_acc(const int* __restrict__ part, const float* __restrict__ x,
                      const float* __restrict__ W_e, float* __restrict__ ac,
                      int n_nodes, int NBP) {
    int n = blockIdx.x * blockDim.x + threadIdx.x;
    if (n >= n_nodes) return;
    int b = n >> BSH, r = n & (BW - 1);
    int ia = 0, ic = 0;
#pragma unroll
    for (int s = 0; s < S_SPLIT; ++s) {
        const int* pp = part + ((size_t)(s * NBP + b)) * (2 * BW);
        ia += pp[r];
        ic += pp[BW + r];
    }
    float a = (float)ia * FXSI, c = (float)ic * FXSI;
    float x0 = x[3*n], x1 = x[3*n+1], x2 = x[3*n+2];
    a += x0 * W_e[8]  + x1 * W_e[9]  + x2 * W_e[10];
    c += x0 * W_e[19] + x1 * W_e[20] + x2 * W_e[21];
    ac[2*n]     = a;
    ac[2*n + 1] = c;
}

// ===========================================================================
// K7: out[e] = sigmoid(a[src] + c[dst] + b_e), 4 edges/thread
// ===========================================================================
__global__ void k_out2(const int* __restrict__ src, const int* __restrict__ dst,
                       const float* __restrict__ ac, const float* __restrict__ b_e,
                       float* __restrict__ out, int n_edges) {
    float bb = b_e[0];
    int e = (blockIdx.x * blockDim.x + threadIdx.x) * 4;
    if (e + 3 < n_edges) {
        int4 s4 = *(const int4*)(src + e);
        int4 d4 = *(const int4*)(dst + e);
        float4 o;
        o.x = sigmoidf(ac[2*s4.x] + ac[2*d4.x + 1] + bb);
        o.y = sigmoidf(ac[2*s4.y] + ac[2*d4.y + 1] + bb);
        o.z = sigmoidf(ac[2*s4.z] + ac[2*d4.z + 1] + bb);
        o.w = sigmoidf(ac[2*s4.w] + ac[2*d4.w + 1] + bb);
        *(float4*)(out + e) = o;
    } else {
        for (int q = e; q < n_edges; ++q)
            out[q] = sigmoidf(ac[2*src[q]] + ac[2*dst[q] + 1] + bb);
    }
}

// ===========================================================================
// FALLBACK (round-1, proven) — only if NB > NBMAX or ws too small.
// ===========================================================================
__global__ void k_nodes(const float* __restrict__ x, const float* __restrict__ W_in,
                        const float* __restrict__ b_in, float* __restrict__ feat,
                        float* __restrict__ H2, int n_nodes) {
    int i = blockIdx.x * blockDim.x + threadIdx.x;
    if (i >= n_nodes) return;
    float x0 = x[3*i], x1 = x[3*i+1], x2 = x[3*i+2];
    float h[8];
#pragma unroll
    for (int c = 0; c < 8; ++c)
        h[c] = tanhf(b_in[c] + x0*W_in[c] + x1*W_in[8+c] + x2*W_in[16+c]);
    float4* fp = (float4*)(feat + (size_t)i * 12);
    fp[0] = make_float4(h[0],h[1],h[2],h[3]);
    fp[1] = make_float4(h[4],h[5],h[6],h[7]);
    fp[2] = make_float4(x0,x1,x2,0.0f);
    float4* hp = (float4*)(H2 + (size_t)i * 8);
    hp[0] = make_float4(0,0,0,0); hp[1] = make_float4(0,0,0,0);
}

__global__ void k_edges(const int* __restrict__ src, const int* __restrict__ dst,
                        const float* __restrict__ feat, const float* __restrict__ W1,
                        const float* __restrict__ b1, const float* __restrict__ W2,
                        const float* __restrict__ b2, float* __restrict__ H2,
                        int n_edges) {
    __shared__ float sW1[176], sW2[64], sb1[8], sb2[8];
    for (int t = threadIdx.x; t < 176; t += blockDim.x) sW1[t] = W1[t];
    for (int t = threadIdx.x; t < 64;  t += blockDim.x) sW2[t] = W2[t];
    if (threadIdx.x < 8) { sb1[threadIdx.x]=b1[threadIdx.x]; sb2[threadIdx.x]=b2[threadIdx.x]; }
    __syncthreads();
    int e = blockIdx.x * blockDim.x + threadIdx.x;
    if (e >= n_edges) return;
    int j = src[e], i = dst[e];
    const float4* fi = (const float4*)(feat + (size_t)i * 12);
    const float4* fj = (const float4*)(feat + (size_t)j * 12);
    float4 i0=fi[0],i1=fi[1],i2=fi[2],j0=fj[0],j1=fj[1],j2=fj[2];
    float xi[11]={i0.x,i0.y,i0.z,i0.w,i1.x,i1.y,i1.z,i1.w,i2.x,i2.y,i2.z};
    float xj[11]={j0.x,j0.y,j0.z,j0.w,j1.x,j1.y,j1.z,j1.w,j2.x,j2.y,j2.z};
    float dd[11];
#pragma unroll
    for (int k = 0; k < 11; ++k) dd[k]=xj[k]-xi[k];
    float m[8];
#pragma unroll
    for (int h = 0; h < 8; ++h) {
        float v = sb1[h];
#pragma unroll
        for (int k = 0; k < 11; ++k) v += xi[k]*sW1[k*8+h];
#pragma unroll
        for (int k = 0; k < 11; ++k) v += dd[k]*sW1[(11+k)*8+h];
        m[h] = sigmoidf(v);
    }
    float m2[8];
#pragma unroll
    for (int h = 0; h < 8; ++h) {
        float v = sb2[h];
#pragma unroll
        for (int k = 0; k < 8; ++k) v += m[k]*sW2[k*8+h];
        m2[h] = sigmoidf(v);
    }
    float* hp = H2 + (size_t)i * 8;
#pragma unroll
    for (int h = 0; h < 8; ++h) atomicAdd(hp + h, m2[h]);
}

__global__ void k_out(const int* __restrict__ src, const int* __restrict__ dst,
                      const float* __restrict__ H2, const float* __restrict__ x,
                      const float* __restrict__ W_e, const float* __restrict__ b_e,
                      float* __restrict__ out, int n_edges) {
    __shared__ float sW[22]; __shared__ float sb;
    if (threadIdx.x < 22) sW[threadIdx.x] = W_e[threadIdx.x];
    if (threadIdx.x == 0) sb = b_e[0];
    __syncthreads();
    int e = blockIdx.x * blockDim.x + threadIdx.x;
    if (e >= n_edges) return;
    int j = src[e], i = dst[e];
    const float4* hj = (const float4*)(H2 + (size_t)j * 8);
    const float4* hi = (const float4*)(H2 + (size_t)i * 8);
    float4 a0=hj[0],a1=hj[1],c0=hi[0],c1=hi[1];
    float acc = sb;
    acc += a0.x*sW[0]+a0.y*sW[1]+a0.z*sW[2]+a0.w*sW[3];
    acc += a1.x*sW[4]+a1.y*sW[5]+a1.z*sW[6]+a1.w*sW[7];
    acc += x[3*(size_t)j]*sW[8]+x[3*(size_t)j+1]*sW[9]+x[3*(size_t)j+2]*sW[10];
    acc += c0.x*sW[11]+c0.y*sW[12]+c0.z*sW[13]+c0.w*sW[14];
    acc += c1.x*sW[15]+c1.y*sW[16]+c1.z*sW[17]+c1.w*sW[18];
    acc += x[3*(size_t)i]*sW[19]+x[3*(size_t)i+1]*sW[20]+x[3*(size_t)i+2]*sW[21];
    out[e] = sigmoidf(acc);
}

// ===========================================================================
extern "C" void kernel_launch(void* const* d_in, const int* in_sizes, int n_in,
                              void* d_out, int out_size, void* d_ws, size_t ws_size,
                              hipStream_t stream) {
    const float* x    = (const float*)d_in[0];
    const int*   ei   = (const int*)d_in[1];
    const float* W_in = (const float*)d_in[2];
    const float* b_in = (const float*)d_in[3];
    const float* W1   = (const float*)d_in[4];
    const float* b1   = (const float*)d_in[5];
    const float* W2   = (const float*)d_in[6];
    const float* b2   = (const float*)d_in[7];
    const float* W_e  = (const float*)d_in[8];
    const float* b_e  = (const float*)d_in[9];

    const int n_nodes = in_sizes[0] / 3;
    const int n_edges = in_sizes[1] / 2;
    const int* src = ei;
    const int* dst = ei + n_edges;
    float* out = (float*)d_out;

    const int NB   = (n_nodes + BW - 1) >> BSH;
    const int NBP  = (NB + 7) & ~7;
    const int NBLK = (n_edges + EPB - 1) / EPB;

    size_t off = 0;
    auto carve = [&](size_t bytes) { size_t o = off; off += (bytes + 255) & ~(size_t)255; return o; };
    char* ws = (char*)d_ws;
    size_t o_egih   = carve((size_t)n_nodes * 8 * 2);
    size_t o_egjh   = carve((size_t)n_nodes * 8 * 2);
    size_t o_ac     = carve((size_t)n_nodes * 2 * 4);
    size_t o_raw    = carve((size_t)NBLK * NB * 4);
    size_t o_rel    = carve((size_t)NBLK * NB * 4);
    size_t o_totals = carve((size_t)NB * 4);
    size_t o_base   = carve(((size_t)NB + 1) * 4);
    size_t o_papcs  = carve(((size_t)n_edges + 4 * NBMAX) * 8);
    size_t o_dls    = carve(((size_t)n_edges + 4 * NBMAX) * 2);
    size_t o_part   = carve((size_t)NBP * S_SPLIT * 2 * BW * 4);
    bool fast = (off <= ws_size) && (NB <= NBMAX);

    if (fast) {
        __half* egih   = (__half*)(ws + o_egih);
        __half* egjh   = (__half*)(ws + o_egjh);
        float*  ac     = (float*)(ws + o_ac);
        int*    raw    = (int*)(ws + o_raw);
        int*    rel    = (int*)(ws + o_rel);
        int*    totals = (int*)(ws + o_totals);
        int*    base   = (int*)(ws + o_base);
        int2*   papcs  = (int2*)(ws + o_papcs);
        unsigned short* dls = (unsigned short*)(ws + o_dls);
        int*    part   = (int*)(ws + o_part);

        k_feat     <<<(n_nodes + TPB - 1) / TPB, TPB, 0, stream>>>(x, W_in, b_in, W1, b1, egih, egjh, n_nodes);
        k_hist2    <<<NBLK, TPB, 0, stream>>>(dst, raw, n_edges, NB);
        k_scan_cols<<<NB, TPB, 0, stream>>>(raw, rel, totals, NB, NBLK);
        k_base     <<<1, NBMAX, 0, stream>>>(totals, base, NB);
        k_fused    <<<NBLK, TPB, 0, stream>>>(src, dst, egih, egjh, W2, b2, W_e,
                                              raw, rel, base, papcs, dls, n_edges, NB);
        k_red      <<<NBP * S_SPLIT, TPB, 0, stream>>>(dls, papcs, base, totals, part, NB, NBP);
        k_acc      <<<(n_nodes + TPB - 1) / TPB, TPB, 0, stream>>>(part, x, W_e, ac, n_nodes, NBP);
        k_out2     <<<(n_edges / 4 + TPB - 1) / TPB + 1, TPB, 0, stream>>>(src, dst, ac, b_e, out, n_edges);
    } else {
        float* feat = (float*)d_ws;
        float* H2   = feat + (size_t)n_nodes * 12;
        k_nodes<<<(n_nodes + TPB - 1) / TPB, TPB, 0, stream>>>(x, W_in, b_in, feat, H2, n_nodes);
        k_edges<<<(n_edges + TPB - 1) / TPB, TPB, 0, stream>>>(src, dst, feat, W1, b1, W2, b2, H2, n_edges);
        k_out  <<<(n_edges + TPB - 1) / TPB, TPB, 0, stream>>>(src, dst, H2, x, W_e, b_e, out, n_edges);
    }
}

// Round 15
// 103.768 us; speedup vs baseline: 1.1977x; 1.1977x over previous
//
#include <hip/hip_runtime.h>
#include <hip/hip_fp16.h>

#define TPB     256
#define BSH     9              // bucket = dst >> 9  (512 nodes / bucket)
#define BW      512
#define EPB     8192           // edges per partition block (32 KB LDS stage)
#define NBMAX   256            // max buckets (n_nodes <= 131072)
#define S_SPLIT 16             // edge-slices per bucket in k_bucket
#define FXS     2097152.0f     // 2^21 fixed-point scale
#define FXSI    (1.0f / 2097152.0f)

static __device__ __forceinline__ float sigmoidf(float v) {
    return __builtin_amdgcn_rcpf(1.0f + __expf(-v));
}

// unpack 8 halves (one uint4) to 8 floats
static __device__ __forceinline__ void unpack8(uint4 u, float o[8]) {
    union { unsigned int u; __half2 h; } c0, c1, c2, c3;
    c0.u = u.x; c1.u = u.y; c2.u = u.z; c3.u = u.w;
    float2 f0 = __half22float2(c0.h), f1 = __half22float2(c1.h);
    float2 f2 = __half22float2(c2.h), f3 = __half22float2(c3.h);
    o[0]=f0.x; o[1]=f0.y; o[2]=f1.x; o[3]=f1.y;
    o[4]=f2.x; o[5]=f2.y; o[6]=f3.x; o[7]=f3.y;
}

// ===========================================================================
// K1 (FAT): blocks [0,NBLK) do the dst-bucket histogram; blocks [NBLK,..)
// do the per-node precompute (gi fp32, gjh fp16). Independent inputs, so
// the ~5µs feat work hides under the BW-bound histogram.
// ===========================================================================
__global__ void k_prep(const float* __restrict__ x,
                       const float* __restrict__ W_in,
                       const float* __restrict__ b_in,
                       const float* __restrict__ W1,
                       const float* __restrict__ b1,
                       float* __restrict__ gi,
                       __half* __restrict__ gjh,
                       const int* __restrict__ dst,
                       int* __restrict__ raw,
                       int n_nodes, int n_edges, int NB, int NBLK) {
    __shared__ int cnt[NBMAX];
    int t = threadIdx.x;
    if ((int)blockIdx.x < NBLK) {
        for (int b = t; b < NB; b += TPB) cnt[b] = 0;
        __syncthreads();
        int e0 = blockIdx.x * EPB;
#pragma unroll
        for (int k = 0; k < EPB / (TPB * 4); ++k) {
            int e = e0 + k * TPB * 4 + t * 4;
            if (e + 3 < n_edges) {
                int4 d4 = *(const int4*)(dst + e);
                atomicAdd(&cnt[d4.x >> BSH], 1);
                atomicAdd(&cnt[d4.y >> BSH], 1);
                atomicAdd(&cnt[d4.z >> BSH], 1);
                atomicAdd(&cnt[d4.w >> BSH], 1);
            } else {
                int qe = min(e + 4, n_edges);
                for (int q = e; q < qe; ++q)
                    atomicAdd(&cnt[dst[q] >> BSH], 1);
            }
        }
        __syncthreads();
        for (int b = t; b < NB; b += TPB)
            raw[(size_t)blockIdx.x * NB + b] = cnt[b];
    } else {
        int n = ((int)blockIdx.x - NBLK) * TPB + t;
        if (n >= n_nodes) return;
        float x0 = x[3*n], x1 = x[3*n+1], x2 = x[3*n+2];
        float f[11];
#pragma unroll
        for (int c = 0; c < 8; ++c)
            f[c] = tanhf(b_in[c] + x0*W_in[c] + x1*W_in[8+c] + x2*W_in[16+c]);
        f[8] = x0; f[9] = x1; f[10] = x2;
        float giv[8], gjv[8];
#pragma unroll
        for (int h = 0; h < 8; ++h) {
            float vi = b1[h], vj = 0.0f;
#pragma unroll
            for (int k = 0; k < 11; ++k) {
                float wa = W1[k*8+h], wb = W1[(11+k)*8+h];
                vi += f[k] * (wa - wb);
                vj += f[k] * wb;
            }
            giv[h] = vi; gjv[h] = vj;
        }
        float4* gip = (float4*)(gi + (size_t)n * 8);
        gip[0] = make_float4(giv[0], giv[1], giv[2], giv[3]);
        gip[1] = make_float4(giv[4], giv[5], giv[6], giv[7]);
        __align__(16) __half hj[8];
#pragma unroll
        for (int k = 0; k < 8; ++k) hj[k] = __float2half_rn(gjv[k]);
        *(uint4*)(gjh + (size_t)n * 8) = *(const uint4*)hj;
    }
}

// ===========================================================================
// K2: per-bucket (column) exclusive scan over blocks: raw -> rel, totals
// ===========================================================================
__global__ void k_scan_cols(const int* __restrict__ raw, int* __restrict__ rel,
                            int* __restrict__ totals, int NB, int NBLK) {
    __shared__ int s[TPB];
    int b = blockIdx.x, t = threadIdx.x;
    int carry = 0;
    for (int q = 0; q < NBLK; q += TPB) {
        int blk = q + t;
        int v = (blk < NBLK) ? raw[(size_t)blk * NB + b] : 0;
        __syncthreads();
        s[t] = v; __syncthreads();
        for (int o = 1; o < TPB; o <<= 1) {
            int u = (t >= o) ? s[t - o] : 0;
            __syncthreads();
            s[t] += u;
            __syncthreads();
        }
        if (blk < NBLK) rel[(size_t)blk * NB + b] = carry + s[t] - v;
        carry += s[TPB - 1];
    }
    if (t == 0) totals[b] = carry;
}

// inline exclusive scan of 4-padded totals -> sbase (NB <= TPB, one chunk)
static __device__ __forceinline__ void base_scan(const int* __restrict__ totals,
                                                 int* s, int* sbase, int NB, int t) {
    int v = (t < NB) ? ((totals[t] + 3) & ~3) : 0;
    s[t] = v; __syncthreads();
    for (int o = 1; o < TPB; o <<= 1) {
        int u = (t >= o) ? s[t - o] : 0;
        __syncthreads();
        s[t] += u;
        __syncthreads();
    }
    if (t < NB) sbase[t] = s[t] - v;
    __syncthreads();
}

// ===========================================================================
// K3: LDS-staged local sort + coalesced run write-out (32 KB stage).
// base computed inline from totals.
// ===========================================================================
__launch_bounds__(TPB)
__global__ void k_scatter(const int* __restrict__ src, const int* __restrict__ dst,
                          const int* __restrict__ raw, const int* __restrict__ rel,
                          const int* __restrict__ totals,
                          int* __restrict__ sorted, int n_edges, int NB) {
    __shared__ int stage[EPB];        // 32 KB
    __shared__ int cnt[NBMAX];
    __shared__ int lscan[NBMAX];
    __shared__ int gd[NBMAX];
    __shared__ int sbase[NBMAX];
    __shared__ int s[TPB];
    int t = threadIdx.x;

    base_scan(totals, s, sbase, NB, t);

    // local exclusive scan of this block's raw counts (NB <= 256: one chunk)
    {
        int v = (t < NB) ? raw[(size_t)blockIdx.x * NB + t] : 0;
        __syncthreads();
        s[t] = v; __syncthreads();
        for (int o = 1; o < TPB; o <<= 1) {
            int u = (t >= o) ? s[t - o] : 0;
            __syncthreads();
            s[t] += u;
            __syncthreads();
        }
        if (t < NB) {
            lscan[t] = s[t] - v;
            cnt[t]   = s[t] - v;
            gd[t]    = sbase[t] + rel[(size_t)blockIdx.x * NB + t];
        }
    }
    __syncthreads();

    int e0 = blockIdx.x * EPB;
#pragma unroll
    for (int k = 0; k < EPB / (TPB * 4); ++k) {
        int e = e0 + k * TPB * 4 + t * 4;
        if (e + 3 < n_edges) {
            int4 s4 = *(const int4*)(src + e);
            int4 d4 = *(const int4*)(dst + e);
            int p;
            p = atomicAdd(&cnt[d4.x >> BSH], 1); stage[p] = (s4.x << BSH) | (d4.x & (BW-1));
            p = atomicAdd(&cnt[d4.y >> BSH], 1); stage[p] = (s4.y << BSH) | (d4.y & (BW-1));
            p = atomicAdd(&cnt[d4.z >> BSH], 1); stage[p] = (s4.z << BSH) | (d4.z & (BW-1));
            p = atomicAdd(&cnt[d4.w >> BSH], 1); stage[p] = (s4.w << BSH) | (d4.w & (BW-1));
        } else {
            int qe = min(e + 4, n_edges);
            for (int q = e; q < qe; ++q) {
                int d = dst[q];
                int p = atomicAdd(&cnt[d >> BSH], 1);
                stage[p] = (src[q] << BSH) | (d & (BW - 1));
            }
        }
    }
    __syncthreads();

    int wid = t >> 6, lane = t & 63;
    for (int b = wid; b < NB; b += (TPB / 64)) {
        int ls = lscan[b];
        int le = cnt[b];
        int g0 = gd[b];
        for (int i = ls + lane; i < le; i += 64)
            sorted[g0 + (i - ls)] = stage[i];
    }
}

// ===========================================================================
// K4: fused per-bucket-slice MLP + reduction (round-12 structure).
//   S_SPLIT=16 -> 3200 blocks for occupancy. Fixed-point int LDS atomics
//   (native ds_add_u32). base computed inline from totals.
// ===========================================================================
__launch_bounds__(TPB, 4)
__global__ void k_bucket(const int* __restrict__ sorted,
                         const int* __restrict__ totals,
                         const float* __restrict__ gi, const __half* __restrict__ gjh,
                         const float* __restrict__ W2, const float* __restrict__ b2,
                         const float* __restrict__ W_e,
                         float* __restrict__ part, int n_nodes, int NB, int NBP) {
    __shared__ int sa[BW], sc[BW];  // 4 KB fixed-point accumulators
    __shared__ int sbase[NBMAX];
    __shared__ int s[TPB];
    int t = threadIdx.x;
    int sl = blockIdx.x / NBP;
    int b  = blockIdx.x - sl * NBP;

    base_scan(totals, s, sbase, NB, t);
    if (b >= NB) return;

    int nb0 = b * BW;
    for (int i = t; i < BW; i += TPB) { sa[i] = 0; sc[i] = 0; }
    __syncthreads();

    int beg = sbase[b];
    int len = totals[b];
    int qs = (((len + S_SPLIT - 1) / S_SPLIT) + 3) & ~3;
    int s0 = beg + sl * qs;
    int s1 = min(beg + len, s0 + qs);

    for (int g = s0 + t * 4; g < s1; g += TPB * 4) {
        if (g + 4 <= s1) {
            int4 pp = *(const int4*)(sorted + g);
            int d[4]  = { pp.x & (BW-1), pp.y & (BW-1), pp.z & (BW-1), pp.w & (BW-1) };
            int sj[4] = { pp.x >> BSH,   pp.y >> BSH,   pp.z >> BSH,   pp.w >> BSH };
            float ej[4][8];
#pragma unroll
            for (int q = 0; q < 4; ++q)
                unpack8(*(const uint4*)(gjh + (size_t)sj[q] * 8), ej[q]);
            float m[4][8];
#pragma unroll
            for (int q = 0; q < 4; ++q) {
                const float4* ip = (const float4*)(gi + (size_t)(nb0 + d[q]) * 8);
                float4 A = ip[0], B = ip[1];
                float ei[8] = {A.x,A.y,A.z,A.w,B.x,B.y,B.z,B.w};
#pragma unroll
                for (int k = 0; k < 8; ++k)
                    m[q][k] = sigmoidf(ei[k] + ej[q][k]);
            }
            float pa[4] = {0,0,0,0}, pc[4] = {0,0,0,0};
#pragma unroll
            for (int h = 0; h < 8; ++h) {
                float bb = b2[h];
                float v[4] = {bb, bb, bb, bb};
#pragma unroll
                for (int k = 0; k < 8; ++k) {
                    float w = W2[k*8+h];
#pragma unroll
                    for (int q = 0; q < 4; ++q) v[q] += m[q][k] * w;
                }
                float wa = W_e[h], wc = W_e[11+h];
#pragma unroll
                for (int q = 0; q < 4; ++q) {
                    float z = sigmoidf(v[q]);
                    pa[q] += z * wa; pc[q] += z * wc;
                }
            }
#pragma unroll
            for (int q = 0; q < 4; ++q) {
                atomicAdd(&sa[d[q]], __float2int_rn(pa[q] * FXS));
                atomicAdd(&sc[d[q]], __float2int_rn(pc[q] * FXS));
            }
        } else {
            for (int e = g; e < s1; ++e) {
                int p = sorted[e];
                int dl = p & (BW - 1);
                float ej[8];
                unpack8(*(const uint4*)(gjh + (size_t)(p >> BSH) * 8), ej);
                const float4* ip = (const float4*)(gi + (size_t)(nb0 + dl) * 8);
                float4 A = ip[0], B = ip[1];
                float ei[8] = {A.x,A.y,A.z,A.w,B.x,B.y,B.z,B.w};
                float m[8];
#pragma unroll
                for (int k = 0; k < 8; ++k) m[k] = sigmoidf(ei[k] + ej[k]);
                float pa = 0, pc = 0;
#pragma unroll
                for (int h = 0; h < 8; ++h) {
                    float v = b2[h];
#pragma unroll
                    for (int k = 0; k < 8; ++k) v += m[k] * W2[k*8+h];
                    float z = sigmoidf(v);
                    pa += z * W_e[h]; pc += z * W_e[11+h];
                }
                atomicAdd(&sa[dl], __float2int_rn(pa * FXS));
                atomicAdd(&sc[dl], __float2int_rn(pc * FXS));
            }
        }
    }
    __syncthreads();
    size_t row = (size_t)blockIdx.x * (2 * BW);
    for (int i = t; i < BW; i += TPB) {
        part[row + i]      = (float)sa[i] * FXSI;
        part[row + BW + i] = (float)sc[i] * FXSI;
    }
}

// ===========================================================================
// K5: reduce S_SPLIT partials + x-projection -> ac[2n], ac[2n+1]
// ===========================================================================
__global__ void k_acc(const float* __restrict__ part, const float* __restrict__ x,
                      const float* __restrict__ W_e, float* __restrict__ ac,
                      int n_nodes, int NBP) {
    int n = blockIdx.x * blockDim.x + threadIdx.x;
    if (n >= n_nodes) return;
    int b = n >> BSH, r = n & (BW - 1);
    float a = 0.0f, c = 0.0f;
#pragma unroll
    for (int s = 0; s < S_SPLIT; ++s) {
        const float* pp = part + ((size_t)(s * NBP + b)) * (2 * BW);
        a += pp[r];
        c += pp[BW + r];
    }
    float x0 = x[3*n], x1 = x[3*n+1], x2 = x[3*n+2];
    a += x0 * W_e[8]  + x1 * W_e[9]  + x2 * W_e[10];
    c += x0 * W_e[19] + x1 * W_e[20] + x2 * W_e[21];
    ac[2*n]     = a;
    ac[2*n + 1] = c;
}

// ===========================================================================
// K6: out[e] = sigmoid(a[src] + c[dst] + b_e), 4 edges/thread
// ===========================================================================
__global__ void k_out2(const int* __restrict__ src, const int* __restrict__ dst,
                       const float* __restrict__ ac, const float* __restrict__ b_e,
                       float* __restrict__ out, int n_edges) {
    float bb = b_e[0];
    int e = (blockIdx.x * blockDim.x + threadIdx.x) * 4;
    if (e + 3 < n_edges) {
        int4 s4 = *(const int4*)(src + e);
        int4 d4 = *(const int4*)(dst + e);
        float4 o;
        o.x = sigmoidf(ac[2*s4.x] + ac[2*d4.x + 1] + bb);
        o.y = sigmoidf(ac[2*s4.y] + ac[2*d4.y + 1] + bb);
        o.z = sigmoidf(ac[2*s4.z] + ac[2*d4.z + 1] + bb);
        o.w = sigmoidf(ac[2*s4.w] + ac[2*d4.w + 1] + bb);
        *(float4*)(out + e) = o;
    } else {
        for (int q = e; q < n_edges; ++q)
            out[q] = sigmoidf(ac[2*src[q]] + ac[2*dst[q] + 1] + bb);
    }
}

// ===========================================================================
// FALLBACK (round-1, proven) — only if NB > NBMAX or ws too small.
// ===========================================================================
__global__ void k_nodes(const float* __restrict__ x, const float* __restrict__ W_in,
                        const float* __restrict__ b_in, float* __restrict__ feat,
                        float* __restrict__ H2, int n_nodes) {
    int i = blockIdx.x * blockDim.x + threadIdx.x;
    if (i >= n_nodes) return;
    float x0 = x[3*i], x1 = x[3*i+1], x2 = x[3*i+2];
    float h[8];
#pragma unroll
    for (int c = 0; c < 8; ++c)
        h[c] = tanhf(b_in[c] + x0*W_in[c] + x1*W_in[8+c] + x2*W_in[16+c]);
    float4* fp = (float4*)(feat + (size_t)i * 12);
    fp[0] = make_float4(h[0],h[1],h[2],h[3]);
    fp[1] = make_float4(h[4],h[5],h[6],h[7]);
    fp[2] = make_float4(x0,x1,x2,0.0f);
    float4* hp = (float4*)(H2 + (size_t)i * 8);
    hp[0] = make_float4(0,0,0,0); hp[1] = make_float4(0,0,0,0);
}

__global__ void k_edges(const int* __restrict__ src, const int* __restrict__ dst,
                        const float* __restrict__ feat, const float* __restrict__ W1,
                        const float* __restrict__ b1, const float* __restrict__ W2,
                        const float* __restrict__ b2, float* __restrict__ H2,
                        int n_edges) {
    __shared__ float sW1[176], sW2[64], sb1[8], sb2[8];
    for (int t = threadIdx.x; t < 176; t += blockDim.x) sW1[t] = W1[t];
    for (int t = threadIdx.x; t < 64;  t += blockDim.x) sW2[t] = W2[t];
    if (threadIdx.x < 8) { sb1[threadIdx.x]=b1[threadIdx.x]; sb2[threadIdx.x]=b2[threadIdx.x]; }
    __syncthreads();
    int e = blockIdx.x * blockDim.x + threadIdx.x;
    if (e >= n_edges) return;
    int j = src[e], i = dst[e];
    const float4* fi = (const float4*)(feat + (size_t)i * 12);
    const float4* fj = (const float4*)(feat + (size_t)j * 12);
    float4 i0=fi[0],i1=fi[1],i2=fi[2],j0=fj[0],j1=fj[1],j2=fj[2];
    float xi[11]={i0.x,i0.y,i0.z,i0.w,i1.x,i1.y,i1.z,i1.w,i2.x,i2.y,i2.z};
    float xj[11]={j0.x,j0.y,j0.z,j0.w,j1.x,j1.y,j1.z,j1.w,j2.x,j2.y,j2.z};
    float dd[11];
#pragma unroll
    for (int k = 0; k < 11; ++k) dd[k]=xj[k]-xi[k];
    float m[8];
#pragma unroll
    for (int h = 0; h < 8; ++h) {
        float v = sb1[h];
#pragma unroll
        for (int k = 0; k < 11; ++k) v += xi[k]*sW1[k*8+h];
#pragma unroll
        for (int k = 0; k < 11; ++k) v += dd[k]*sW1[(11+k)*8+h];
        m[h] = sigmoidf(v);
    }
    float m2[8];
#pragma unroll
    for (int h = 0; h < 8; ++h) {
        float v = sb2[h];
#pragma unroll
        for (int k = 0; k < 8; ++k) v += m[k]*sW2[k*8+h];
        m2[h] = sigmoidf(v);
    }
    float* hp = H2 + (size_t)i * 8;
#pragma unroll
    for (int h = 0; h < 8; ++h) atomicAdd(hp + h, m2[h]);
}

__global__ void k_out(const int* __restrict__ src, const int* __restrict__ dst,
                      const float* __restrict__ H2, const float* __restrict__ x,
                      const float* __restrict__ W_e, const float* __restrict__ b_e,
                      float* __restrict__ out, int n_edges) {
    __shared__ float sW[22]; __shared__ float sb;
    if (threadIdx.x < 22) sW[threadIdx.x] = W_e[threadIdx.x];
    if (threadIdx.x == 0) sb = b_e[0];
    __syncthreads();
    int e = blockIdx.x * blockDim.x + threadIdx.x;
    if (e >= n_edges) return;
    int j = src[e], i = dst[e];
    const float4* hj = (const float4*)(H2 + (size_t)j * 8);
    const float4* hi = (const float4*)(H2 + (size_t)i * 8);
    float4 a0=hj[0],a1=hj[1],c0=hi[0],c1=hi[1];
    float acc = sb;
    acc += a0.x*sW[0]+a0.y*sW[1]+a0.z*sW[2]+a0.w*sW[3];
    acc += a1.x*sW[4]+a1.y*sW[5]+a1.z*sW[6]+a1.w*sW[7];
    acc += x[3*(size_t)j]*sW[8]+x[3*(size_t)j+1]*sW[9]+x[3*(size_t)j+2]*sW[10];
    acc += c0.x*sW[11]+c0.y*sW[12]+c0.z*sW[13]+c0.w*sW[14];
    acc += c1.x*sW[15]+c1.y*sW[16]+c1.z*sW[17]+c1.w*sW[18];
    acc += x[3*(size_t)i]*sW[19]+x[3*(size_t)i+1]*sW[20]+x[3*(size_t)i+2]*sW[21];
    out[e] = sigmoidf(acc);
}

// ===========================================================================
extern "C" void kernel_launch(void* const* d_in, const int* in_sizes, int n_in,
                              void* d_out, int out_size, void* d_ws, size_t ws_size,
                              hipStream_t stream) {
    const float* x    = (const float*)d_in[0];
    const int*   ei   = (const int*)d_in[1];
    const float* W_in = (const float*)d_in[2];
    const float* b_in = (const float*)d_in[3];
    const float* W1   = (const float*)d_in[4];
    const float* b1   = (const float*)d_in[5];
    const float* W2   = (const float*)d_in[6];
    const float* b2   = (const float*)d_in[7];
    const float* W_e  = (const float*)d_in[8];
    const float* b_e  = (const float*)d_in[9];

    const int n_nodes = in_sizes[0] / 3;
    const int n_edges = in_sizes[1] / 2;
    const int* src = ei;
    const int* dst = ei + n_edges;
    float* out = (float*)d_out;

    const int NB   = (n_nodes + BW - 1) >> BSH;
    const int NBP  = (NB + 7) & ~7;
    const int NBLK = (n_edges + EPB - 1) / EPB;
    const int NFB  = (n_nodes + TPB - 1) / TPB;   // feat blocks

    size_t off = 0;
    auto carve = [&](size_t bytes) { size_t o = off; off += (bytes + 255) & ~(size_t)255; return o; };
    char* ws = (char*)d_ws;
    size_t o_gi     = carve((size_t)n_nodes * 8 * 4);
    size_t o_gjh    = carve((size_t)n_nodes * 8 * 2);
    size_t o_ac     = carve((size_t)n_nodes * 2 * 4);
    size_t o_raw    = carve((size_t)NBLK * NB * 4);
    size_t o_rel    = carve((size_t)NBLK * NB * 4);
    size_t o_totals = carve((size_t)NB * 4);
    size_t o_sorted = carve(((size_t)n_edges + 4 * NBMAX) * 4);
    size_t o_part   = carve((size_t)NBP * S_SPLIT * 2 * BW * 4);
    bool fast = (off <= ws_size) && (NB <= NBMAX);

    if (fast) {
        float*  gi     = (float*)(ws + o_gi);
        __half* gjh    = (__half*)(ws + o_gjh);
        float*  ac     = (float*)(ws + o_ac);
        int*    raw    = (int*)(ws + o_raw);
        int*    rel    = (int*)(ws + o_rel);
        int*    totals = (int*)(ws + o_totals);
        int*    sorted = (int*)(ws + o_sorted);
        float*  part   = (float*)(ws + o_part);

        k_prep     <<<NBLK + NFB, TPB, 0, stream>>>(x, W_in, b_in, W1, b1, gi, gjh,
                                                    dst, raw, n_nodes, n_edges, NB, NBLK);
        k_scan_cols<<<NB, TPB, 0, stream>>>(raw, rel, totals, NB, NBLK);
        k_scatter  <<<NBLK, TPB, 0, stream>>>(src, dst, raw, rel, totals, sorted, n_edges, NB);
        k_bucket   <<<NBP * S_SPLIT, TPB, 0, stream>>>(sorted, totals, gi, gjh, W2, b2, W_e,
                                                       part, n_nodes, NB, NBP);
        k_acc      <<<(n_nodes + TPB - 1) / TPB, TPB, 0, stream>>>(part, x, W_e, ac, n_nodes, NBP);
        k_out2     <<<(n_edges / 4 + TPB - 1) / TPB + 1, TPB, 0, stream>>>(src, dst, ac, b_e, out, n_edges);
    } else {
        float* feat = (float*)d_ws;
        float* H2   = feat + (size_t)n_nodes * 12;
        k_nodes<<<(n_nodes + TPB - 1) / TPB, TPB, 0, stream>>>(x, W_in, b_in, feat, H2, n_nodes);
        k_edges<<<(n_edges + TPB - 1) / TPB, TPB, 0, stream>>>(src, dst, feat, W1, b1, W2, b2, H2, n_edges);
        k_out  <<<(n_edges + TPB - 1) / TPB, TPB, 0, stream>>>(src, dst, H2, x, W_e, b_e, out, n_edges);
    }
}

// Round 16
// 99.996 us; speedup vs baseline: 1.2429x; 1.0377x over previous
//
#include <hip/hip_runtime.h>
#include <hip/hip_fp16.h>

#define TPB     256
#define BSH     9              // bucket = dst >> 9  (512 nodes / bucket)
#define BW      512
#define EPB     8192           // edges per partition block (32 KB LDS stage)
#define NBMAX   256            // max buckets (n_nodes <= 131072)
#define S_SPLIT 16             // edge-slices per bucket in k_bucket
#define FXS     2097152.0f     // 2^21 fixed-point scale
#define FXSI    (1.0f / 2097152.0f)

static __device__ __forceinline__ float sigmoidf(float v) {
    return __builtin_amdgcn_rcpf(1.0f + __expf(-v));
}

// unpack 8 halves (one uint4) to 8 floats
static __device__ __forceinline__ void unpack8(uint4 u, float o[8]) {
    union { unsigned int u; __half2 h; } c0, c1, c2, c3;
    c0.u = u.x; c1.u = u.y; c2.u = u.z; c3.u = u.w;
    float2 f0 = __half22float2(c0.h), f1 = __half22float2(c1.h);
    float2 f2 = __half22float2(c2.h), f3 = __half22float2(c3.h);
    o[0]=f0.x; o[1]=f0.y; o[2]=f1.x; o[3]=f1.y;
    o[4]=f2.x; o[5]=f2.y; o[6]=f3.x; o[7]=f3.y;
}

// ===========================================================================
// K1 (FAT): blocks [0,NBLK) histogram dst-buckets; blocks [NBLK,..) compute
// per-node exp-form tables: egi[n]=exp(-(f@(W1a-W1b)+b1)) fp32,
// egjh[n]=exp(-(f@W1b)) fp16. L1 sigmoid per edge = rcp(1+ei*ej).
// ===========================================================================
__global__ void k_prep(const float* __restrict__ x,
                       const float* __restrict__ W_in,
                       const float* __restrict__ b_in,
                       const float* __restrict__ W1,
                       const float* __restrict__ b1,
                       float* __restrict__ egi,
                       __half* __restrict__ egjh,
                       const int* __restrict__ dst,
                       int* __restrict__ raw,
                       int n_nodes, int n_edges, int NB, int NBLK) {
    __shared__ int cnt[NBMAX];
    int t = threadIdx.x;
    if ((int)blockIdx.x < NBLK) {
        for (int b = t; b < NB; b += TPB) cnt[b] = 0;
        __syncthreads();
        int e0 = blockIdx.x * EPB;
#pragma unroll
        for (int k = 0; k < EPB / (TPB * 4); ++k) {
            int e = e0 + k * TPB * 4 + t * 4;
            if (e + 3 < n_edges) {
                int4 d4 = *(const int4*)(dst + e);
                atomicAdd(&cnt[d4.x >> BSH], 1);
                atomicAdd(&cnt[d4.y >> BSH], 1);
                atomicAdd(&cnt[d4.z >> BSH], 1);
                atomicAdd(&cnt[d4.w >> BSH], 1);
            } else {
                int qe = min(e + 4, n_edges);
                for (int q = e; q < qe; ++q)
                    atomicAdd(&cnt[dst[q] >> BSH], 1);
            }
        }
        __syncthreads();
        for (int b = t; b < NB; b += TPB)
            raw[(size_t)blockIdx.x * NB + b] = cnt[b];
    } else {
        int n = ((int)blockIdx.x - NBLK) * TPB + t;
        if (n >= n_nodes) return;
        float x0 = x[3*n], x1 = x[3*n+1], x2 = x[3*n+2];
        float f[11];
#pragma unroll
        for (int c = 0; c < 8; ++c)
            f[c] = tanhf(b_in[c] + x0*W_in[c] + x1*W_in[8+c] + x2*W_in[16+c]);
        f[8] = x0; f[9] = x1; f[10] = x2;
        float giv[8], gjv[8];
#pragma unroll
        for (int h = 0; h < 8; ++h) {
            float vi = b1[h], vj = 0.0f;
#pragma unroll
            for (int k = 0; k < 11; ++k) {
                float wa = W1[k*8+h], wb = W1[(11+k)*8+h];
                vi += f[k] * (wa - wb);
                vj += f[k] * wb;
            }
            giv[h] = __expf(-vi); gjv[h] = __expf(-vj);
        }
        float4* gip = (float4*)(egi + (size_t)n * 8);
        gip[0] = make_float4(giv[0], giv[1], giv[2], giv[3]);
        gip[1] = make_float4(giv[4], giv[5], giv[6], giv[7]);
        __align__(16) __half hj[8];
#pragma unroll
        for (int k = 0; k < 8; ++k) hj[k] = __float2half_rn(gjv[k]);
        *(uint4*)(egjh + (size_t)n * 8) = *(const uint4*)hj;
    }
}

// ===========================================================================
// K2: per-bucket (column) exclusive scan over blocks: raw -> rel, totals
// ===========================================================================
__global__ void k_scan_cols(const int* __restrict__ raw, int* __restrict__ rel,
                            int* __restrict__ totals, int NB, int NBLK) {
    __shared__ int s[TPB];
    int b = blockIdx.x, t = threadIdx.x;
    int carry = 0;
    for (int q = 0; q < NBLK; q += TPB) {
        int blk = q + t;
        int v = (blk < NBLK) ? raw[(size_t)blk * NB + b] : 0;
        __syncthreads();
        s[t] = v; __syncthreads();
        for (int o = 1; o < TPB; o <<= 1) {
            int u = (t >= o) ? s[t - o] : 0;
            __syncthreads();
            s[t] += u;
            __syncthreads();
        }
        if (blk < NBLK) rel[(size_t)blk * NB + b] = carry + s[t] - v;
        carry += s[TPB - 1];
    }
    if (t == 0) totals[b] = carry;
}

// K2b: exclusive scan of 4-padded totals -> base (1 block, trivial)
__global__ void k_base(const int* __restrict__ totals, int* __restrict__ base,
                       int NB) {
    __shared__ int s[NBMAX];
    int t = threadIdx.x;
    int v = (t < NB) ? ((totals[t] + 3) & ~3) : 0;
    s[t] = v; __syncthreads();
    for (int o = 1; o < NBMAX; o <<= 1) {
        int u = (t >= o) ? s[t - o] : 0;
        __syncthreads();
        s[t] += u;
        __syncthreads();
    }
    if (t < NB) base[t] = s[t] - v;
}

// ===========================================================================
// K3: LDS-staged local sort + coalesced run write-out (32 KB stage).
// ===========================================================================
__launch_bounds__(TPB)
__global__ void k_scatter(const int* __restrict__ src, const int* __restrict__ dst,
                          const int* __restrict__ raw, const int* __restrict__ rel,
                          const int* __restrict__ base,
                          int* __restrict__ sorted, int n_edges, int NB) {
    __shared__ int stage[EPB];        // 32 KB
    __shared__ int cnt[NBMAX];
    __shared__ int lscan[NBMAX];
    __shared__ int gd[NBMAX];
    __shared__ int s[TPB];
    int t = threadIdx.x;

    // local exclusive scan of this block's raw counts (NB <= 256: one chunk)
    {
        int v = (t < NB) ? raw[(size_t)blockIdx.x * NB + t] : 0;
        s[t] = v; __syncthreads();
        for (int o = 1; o < TPB; o <<= 1) {
            int u = (t >= o) ? s[t - o] : 0;
            __syncthreads();
            s[t] += u;
            __syncthreads();
        }
        if (t < NB) {
            lscan[t] = s[t] - v;
            cnt[t]   = s[t] - v;
            gd[t]    = base[t] + rel[(size_t)blockIdx.x * NB + t];
        }
    }
    __syncthreads();

    int e0 = blockIdx.x * EPB;
#pragma unroll
    for (int k = 0; k < EPB / (TPB * 4); ++k) {
        int e = e0 + k * TPB * 4 + t * 4;
        if (e + 3 < n_edges) {
            int4 s4 = *(const int4*)(src + e);
            int4 d4 = *(const int4*)(dst + e);
            int p;
            p = atomicAdd(&cnt[d4.x >> BSH], 1); stage[p] = (s4.x << BSH) | (d4.x & (BW-1));
            p = atomicAdd(&cnt[d4.y >> BSH], 1); stage[p] = (s4.y << BSH) | (d4.y & (BW-1));
            p = atomicAdd(&cnt[d4.z >> BSH], 1); stage[p] = (s4.z << BSH) | (d4.z & (BW-1));
            p = atomicAdd(&cnt[d4.w >> BSH], 1); stage[p] = (s4.w << BSH) | (d4.w & (BW-1));
        } else {
            int qe = min(e + 4, n_edges);
            for (int q = e; q < qe; ++q) {
                int d = dst[q];
                int p = atomicAdd(&cnt[d >> BSH], 1);
                stage[p] = (src[q] << BSH) | (d & (BW - 1));
            }
        }
    }
    __syncthreads();

    int wid = t >> 6, lane = t & 63;
    for (int b = wid; b < NB; b += (TPB / 64)) {
        int ls = lscan[b];
        int le = cnt[b];
        int g0 = gd[b];
        for (int i = ls + lane; i < le; i += 64)
            sorted[g0 + (i - ls)] = stage[i];
    }
}

// ===========================================================================
// K4: fused per-bucket-slice MLP + reduction.
//   S_SPLIT=16, light preamble (zero 4KB only), exp-form L1 (no exp),
//   fixed-point int LDS atomics, int part output (exact).
// ===========================================================================
__launch_bounds__(TPB, 4)
__global__ void k_bucket(const int* __restrict__ sorted, const int* __restrict__ base,
                         const int* __restrict__ totals,
                         const float* __restrict__ egi, const __half* __restrict__ egjh,
                         const float* __restrict__ W2, const float* __restrict__ b2,
                         const float* __restrict__ W_e,
                         int* __restrict__ part, int n_nodes, int NB, int NBP) {
    __shared__ int sa[BW], sc[BW];  // 4 KB fixed-point accumulators
    int t = threadIdx.x;
    int sl = blockIdx.x / NBP;
    int b  = blockIdx.x - sl * NBP;
    if (b >= NB) return;

    int nb0 = b * BW;
    for (int i = t; i < BW; i += TPB) { sa[i] = 0; sc[i] = 0; }
    __syncthreads();

    int beg = base[b];
    int len = totals[b];
    int qs = (((len + S_SPLIT - 1) / S_SPLIT) + 3) & ~3;
    int s0 = beg + sl * qs;
    int s1 = min(beg + len, s0 + qs);

    for (int g = s0 + t * 4; g < s1; g += TPB * 4) {
        if (g + 4 <= s1) {
            int4 pp = *(const int4*)(sorted + g);
            int d[4]  = { pp.x & (BW-1), pp.y & (BW-1), pp.z & (BW-1), pp.w & (BW-1) };
            int sj[4] = { pp.x >> BSH,   pp.y >> BSH,   pp.z >> BSH,   pp.w >> BSH };
            float ej[4][8];
#pragma unroll
            for (int q = 0; q < 4; ++q)
                unpack8(*(const uint4*)(egjh + (size_t)sj[q] * 8), ej[q]);
            float m[4][8];
#pragma unroll
            for (int q = 0; q < 4; ++q) {
                const float4* ip = (const float4*)(egi + (size_t)(nb0 + d[q]) * 8);
                float4 A = ip[0], B = ip[1];
                float ei[8] = {A.x,A.y,A.z,A.w,B.x,B.y,B.z,B.w};
#pragma unroll
                for (int k = 0; k < 8; ++k)
                    m[q][k] = __builtin_amdgcn_rcpf(1.0f + ei[k] * ej[q][k]);
            }
            float pa[4] = {0,0,0,0}, pc[4] = {0,0,0,0};
#pragma unroll
            for (int h = 0; h < 8; ++h) {
                float bb = b2[h];
                float v[4] = {bb, bb, bb, bb};
#pragma unroll
                for (int k = 0; k < 8; ++k) {
                    float w = W2[k*8+h];
#pragma unroll
                    for (int q = 0; q < 4; ++q) v[q] += m[q][k] * w;
                }
                float wa = W_e[h], wc = W_e[11+h];
#pragma unroll
                for (int q = 0; q < 4; ++q) {
                    float z = sigmoidf(v[q]);
                    pa[q] += z * wa; pc[q] += z * wc;
                }
            }
#pragma unroll
            for (int q = 0; q < 4; ++q) {
                atomicAdd(&sa[d[q]], __float2int_rn(pa[q] * FXS));
                atomicAdd(&sc[d[q]], __float2int_rn(pc[q] * FXS));
            }
        } else {
            for (int e = g; e < s1; ++e) {
                int p = sorted[e];
                int dl = p & (BW - 1);
                float ej[8];
                unpack8(*(const uint4*)(egjh + (size_t)(p >> BSH) * 8), ej);
                const float4* ip = (const float4*)(egi + (size_t)(nb0 + dl) * 8);
                float4 A = ip[0], B = ip[1];
                float ei[8] = {A.x,A.y,A.z,A.w,B.x,B.y,B.z,B.w};
                float m[8];
#pragma unroll
                for (int k = 0; k < 8; ++k)
                    m[k] = __builtin_amdgcn_rcpf(1.0f + ei[k] * ej[k]);
                float pa = 0, pc = 0;
#pragma unroll
                for (int h = 0; h < 8; ++h) {
                    float v = b2[h];
#pragma unroll
                    for (int k = 0; k < 8; ++k) v += m[k] * W2[k*8+h];
                    float z = sigmoidf(v);
                    pa += z * W_e[h]; pc += z * W_e[11+h];
                }
                atomicAdd(&sa[dl], __float2int_rn(pa * FXS));
                atomicAdd(&sc[dl], __float2int_rn(pc * FXS));
            }
        }
    }
    __syncthreads();
    size_t row = (size_t)blockIdx.x * (2 * BW);
    for (int i = t; i < BW; i += TPB) {
        part[row + i]      = sa[i];
        part[row + BW + i] = sc[i];
    }
}

// ===========================================================================
// K5: reduce S_SPLIT int partials (exact) + x-projection -> ac[2n], ac[2n+1]
// ===========================================================================
__global__ void k_acc(const int* __restrict__ part, const float* __restrict__ x,
                      const float* __restrict__ W_e, float* __restrict__ ac,
                      int n_nodes, int NBP) {
    int n = blockIdx.x * blockDim.x + threadIdx.x;
    if (n >= n_nodes) return;
    int b = n >> BSH, r = n & (BW - 1);
    int ia = 0, ic = 0;
#pragma unroll
    for (int s = 0; s < S_SPLIT; ++s) {
        const int* pp = part + ((size_t)(s * NBP + b)) * (2 * BW);
        ia += pp[r];
        ic += pp[BW + r];
    }
    float a = (float)ia * FXSI, c = (float)ic * FXSI;
    float x0 = x[3*n], x1 = x[3*n+1], x2 = x[3*n+2];
    a += x0 * W_e[8]  + x1 * W_e[9]  + x2 * W_e[10];
    c += x0 * W_e[19] + x1 * W_e[20] + x2 * W_e[21];
    ac[2*n]     = a;
    ac[2*n + 1] = c;
}

// ===========================================================================
// K6: out[e] = sigmoid(a[src] + c[dst] + b_e), 4 edges/thread
// ===========================================================================
__global__ void k_out2(const int* __restrict__ src, const int* __restrict__ dst,
                       const float* __restrict__ ac, const float* __restrict__ b_e,
                       float* __restrict__ out, int n_edges) {
    float bb = b_e[0];
    int e = (blockIdx.x * blockDim.x + threadIdx.x) * 4;
    if (e + 3 < n_edges) {
        int4 s4 = *(const int4*)(src + e);
        int4 d4 = *(const int4*)(dst + e);
        float4 o;
        o.x = sigmoidf(ac[2*s4.x] + ac[2*d4.x + 1] + bb);
        o.y = sigmoidf(ac[2*s4.y] + ac[2*d4.y + 1] + bb);
        o.z = sigmoidf(ac[2*s4.z] + ac[2*d4.z + 1] + bb);
        o.w = sigmoidf(ac[2*s4.w] + ac[2*d4.w + 1] + bb);
        *(float4*)(out + e) = o;
    } else {
        for (int q = e; q < n_edges; ++q)
            out[q] = sigmoidf(ac[2*src[q]] + ac[2*dst[q] + 1] + bb);
    }
}

// ===========================================================================
// FALLBACK (round-1, proven) — only if NB > NBMAX or ws too small.
// ===========================================================================
__global__ void k_nodes(const float* __restrict__ x, const float* __restrict__ W_in,
                        const float* __restrict__ b_in, float* __restrict__ feat,
                        float* __restrict__ H2, int n_nodes) {
    int i = blockIdx.x * blockDim.x + threadIdx.x;
    if (i >= n_nodes) return;
    float x0 = x[3*i], x1 = x[3*i+1], x2 = x[3*i+2];
    float h[8];
#pragma unroll
    for (int c = 0; c < 8; ++c)
        h[c] = tanhf(b_in[c] + x0*W_in[c] + x1*W_in[8+c] + x2*W_in[16+c]);
    float4* fp = (float4*)(feat + (size_t)i * 12);
    fp[0] = make_float4(h[0],h[1],h[2],h[3]);
    fp[1] = make_float4(h[4],h[5],h[6],h[7]);
    fp[2] = make_float4(x0,x1,x2,0.0f);
    float4* hp = (float4*)(H2 + (size_t)i * 8);
    hp[0] = make_float4(0,0,0,0); hp[1] = make_float4(0,0,0,0);
}

__global__ void k_edges(const int* __restrict__ src, const int* __restrict__ dst,
                        const float* __restrict__ feat, const float* __restrict__ W1,
                        const float* __restrict__ b1, const float* __restrict__ W2,
                        const float* __restrict__ b2, float* __restrict__ H2,
                        int n_edges) {
    __shared__ float sW1[176], sW2[64], sb1[8], sb2[8];
    for (int t = threadIdx.x; t < 176; t += blockDim.x) sW1[t] = W1[t];
    for (int t = threadIdx.x; t < 64;  t += blockDim.x) sW2[t] = W2[t];
    if (threadIdx.x < 8) { sb1[threadIdx.x]=b1[threadIdx.x]; sb2[threadIdx.x]=b2[threadIdx.x]; }
    __syncthreads();
    int e = blockIdx.x * blockDim.x + threadIdx.x;
    if (e >= n_edges) return;
    int j = src[e], i = dst[e];
    const float4* fi = (const float4*)(feat + (size_t)i * 12);
    const float4* fj = (const float4*)(feat + (size_t)j * 12);
    float4 i0=fi[0],i1=fi[1],i2=fi[2],j0=fj[0],j1=fj[1],j2=fj[2];
    float xi[11]={i0.x,i0.y,i0.z,i0.w,i1.x,i1.y,i1.z,i1.w,i2.x,i2.y,i2.z};
    float xj[11]={j0.x,j0.y,j0.z,j0.w,j1.x,j1.y,j1.z,j1.w,j2.x,j2.y,j2.z};
    float dd[11];
#pragma unroll
    for (int k = 0; k < 11; ++k) dd[k]=xj[k]-xi[k];
    float m[8];
#pragma unroll
    for (int h = 0; h < 8; ++h) {
        float v = sb1[h];
#pragma unroll
        for (int k = 0; k < 11; ++k) v += xi[k]*sW1[k*8+h];
#pragma unroll
        for (int k = 0; k < 11; ++k) v += dd[k]*sW1[(11+k)*8+h];
        m[h] = sigmoidf(v);
    }
    float m2[8];
#pragma unroll
    for (int h = 0; h < 8; ++h) {
        float v = sb2[h];
#pragma unroll
        for (int k = 0; k < 8; ++k) v += m[k]*sW2[k*8+h];
        m2[h] = sigmoidf(v);
    }
    float* hp = H2 + (size_t)i * 8;
#pragma unroll
    for (int h = 0; h < 8; ++h) atomicAdd(hp + h, m2[h]);
}

__global__ void k_out(const int* __restrict__ src, const int* __restrict__ dst,
                      const float* __restrict__ H2, const float* __restrict__ x,
                      const float* __restrict__ W_e, const float* __restrict__ b_e,
                      float* __restrict__ out, int n_edges) {
    __shared__ float sW[22]; __shared__ float sb;
    if (threadIdx.x < 22) sW[threadIdx.x] = W_e[threadIdx.x];
    if (threadIdx.x == 0) sb = b_e[0];
    __syncthreads();
    int e = blockIdx.x * blockDim.x + threadIdx.x;
    if (e >= n_edges) return;
    int j = src[e], i = dst[e];
    const float4* hj = (const float4*)(H2 + (size_t)j * 8);
    const float4* hi = (const float4*)(H2 + (size_t)i * 8);
    float4 a0=hj[0],a1=hj[1],c0=hi[0],c1=hi[1];
    float acc = sb;
    acc += a0.x*sW[0]+a0.y*sW[1]+a0.z*sW[2]+a0.w*sW[3];
    acc += a1.x*sW[4]+a1.y*sW[5]+a1.z*sW[6]+a1.w*sW[7];
    acc += x[3*(size_t)j]*sW[8]+x[3*(size_t)j+1]*sW[9]+x[3*(size_t)j+2]*sW[10];
    acc += c0.x*sW[11]+c0.y*sW[12]+c0.z*sW[13]+c0.w*sW[14];
    acc += c1.x*sW[15]+c1.y*sW[16]+c1.z*sW[17]+c1.w*sW[18];
    acc += x[3*(size_t)i]*sW[19]+x[3*(size_t)i+1]*sW[20]+x[3*(size_t)i+2]*sW[21];
    out[e] = sigmoidf(acc);
}

// ===========================================================================
extern "C" void kernel_launch(void* const* d_in, const int* in_sizes, int n_in,
                              void* d_out, int out_size, void* d_ws, size_t ws_size,
                              hipStream_t stream) {
    const float* x    = (const float*)d_in[0];
    const int*   ei   = (const int*)d_in[1];
    const float* W_in = (const float*)d_in[2];
    const float* b_in = (const float*)d_in[3];
    const float* W1   = (const float*)d_in[4];
    const float* b1   = (const float*)d_in[5];
    const float* W2   = (const float*)d_in[6];
    const float* b2   = (const float*)d_in[7];
    const float* W_e  = (const float*)d_in[8];
    const float* b_e  = (const float*)d_in[9];

    const int n_nodes = in_sizes[0] / 3;
    const int n_edges = in_sizes[1] / 2;
    const int* src = ei;
    const int* dst = ei + n_edges;
    float* out = (float*)d_out;

    const int NB   = (n_nodes + BW - 1) >> BSH;
    const int NBP  = (NB + 7) & ~7;
    const int NBLK = (n_edges + EPB - 1) / EPB;
    const int NFB  = (n_nodes + TPB - 1) / TPB;

    size_t off = 0;
    auto carve = [&](size_t bytes) { size_t o = off; off += (bytes + 255) & ~(size_t)255; return o; };
    char* ws = (char*)d_ws;
    size_t o_egi    = carve((size_t)n_nodes * 8 * 4);
    size_t o_egjh   = carve((size_t)n_nodes * 8 * 2);
    size_t o_ac     = carve((size_t)n_nodes * 2 * 4);
    size_t o_raw    = carve((size_t)NBLK * NB * 4);
    size_t o_rel    = carve((size_t)NBLK * NB * 4);
    size_t o_totals = carve((size_t)NB * 4);
    size_t o_base   = carve(((size_t)NB + 1) * 4);
    size_t o_sorted = carve(((size_t)n_edges + 4 * NBMAX) * 4);
    size_t o_part   = carve((size_t)NBP * S_SPLIT * 2 * BW * 4);
    bool fast = (off <= ws_size) && (NB <= NBMAX);

    if (fast) {
        float*  egi    = (float*)(ws + o_egi);
        __half* egjh   = (__half*)(ws + o_egjh);
        float*  ac     = (float*)(ws + o_ac);
        int*    raw    = (int*)(ws + o_raw);
        int*    rel    = (int*)(ws + o_rel);
        int*    totals = (int*)(ws + o_totals);
        int*    base   = (int*)(ws + o_base);
        int*    sorted = (int*)(ws + o_sorted);
        int*    part   = (int*)(ws + o_part);

        k_prep     <<<NBLK + NFB, TPB, 0, stream>>>(x, W_in, b_in, W1, b1, egi, egjh,
                                                    dst, raw, n_nodes, n_edges, NB, NBLK);
        k_scan_cols<<<NB, TPB, 0, stream>>>(raw, rel, totals, NB, NBLK);
        k_base     <<<1, NBMAX, 0, stream>>>(totals, base, NB);
        k_scatter  <<<NBLK, TPB, 0, stream>>>(src, dst, raw, rel, base, sorted, n_edges, NB);
        k_bucket   <<<NBP * S_SPLIT, TPB, 0, stream>>>(sorted, base, totals, egi, egjh, W2, b2, W_e,
                                                       part, n_nodes, NB, NBP);
        k_acc      <<<(n_nodes + TPB - 1) / TPB, TPB, 0, stream>>>(part, x, W_e, ac, n_nodes, NBP);
        k_out2     <<<(n_edges / 4 + TPB - 1) / TPB + 1, TPB, 0, stream>>>(src, dst, ac, b_e, out, n_edges);
    } else {
        float* feat = (float*)d_ws;
        float* H2   = feat + (size_t)n_nodes * 12;
        k_nodes<<<(n_nodes + TPB - 1) / TPB, TPB, 0, stream>>>(x, W_in, b_in, feat, H2, n_nodes);
        k_edges<<<(n_edges + TPB - 1) / TPB, TPB, 0, stream>>>(src, dst, feat, W1, b1, W2, b2, H2, n_edges);
        k_out  <<<(n_edges + TPB - 1) / TPB, TPB, 0, stream>>>(src, dst, H2, x, W_e, b_e, out, n_edges);
    }
}

// Round 17
// 99.198 us; speedup vs baseline: 1.2529x; 1.0080x over previous
//
#include <hip/hip_runtime.h>
#include <hip/hip_fp16.h>

#define TPB     256
#define BSH     9              // bucket = dst >> 9  (512 nodes / bucket)
#define BW      512
#define EPB     8192           // edges per partition block (32 KB LDS stage)
#define NBMAX   256            // max buckets (n_nodes <= 131072)
#define S_SPLIT 16             // edge-slices per bucket in k_bucket
#define FXS     2097152.0f     // 2^21 fixed-point scale
#define FXSI    (1.0f / 2097152.0f)

static __device__ __forceinline__ float sigmoidf(float v) {
    return __builtin_amdgcn_rcpf(1.0f + __expf(-v));
}

// unpack 8 halves (one uint4) to 8 floats
static __device__ __forceinline__ void unpack8(uint4 u, float o[8]) {
    union { unsigned int u; __half2 h; } c0, c1, c2, c3;
    c0.u = u.x; c1.u = u.y; c2.u = u.z; c3.u = u.w;
    float2 f0 = __half22float2(c0.h), f1 = __half22float2(c1.h);
    float2 f2 = __half22float2(c2.h), f3 = __half22float2(c3.h);
    o[0]=f0.x; o[1]=f0.y; o[2]=f1.x; o[3]=f1.y;
    o[4]=f2.x; o[5]=f2.y; o[6]=f3.x; o[7]=f3.y;
}

// ===========================================================================
// K1 (FAT): blocks [0,NBLK) histogram dst-buckets; blocks [NBLK,..) compute
// per-node exp-form tables: egi[n]=exp(-(f@(W1a-W1b)+b1)) fp32,
// egjh[n]=exp(-(f@W1b)) fp16. L1 sigmoid per edge = rcp(1+ei*ej).
// ===========================================================================
__global__ void k_prep(const float* __restrict__ x,
                       const float* __restrict__ W_in,
                       const float* __restrict__ b_in,
                       const float* __restrict__ W1,
                       const float* __restrict__ b1,
                       float* __restrict__ egi,
                       __half* __restrict__ egjh,
                       const int* __restrict__ dst,
                       int* __restrict__ raw,
                       int n_nodes, int n_edges, int NB, int NBLK) {
    __shared__ int cnt[NBMAX];
    int t = threadIdx.x;
    if ((int)blockIdx.x < NBLK) {
        for (int b = t; b < NB; b += TPB) cnt[b] = 0;
        __syncthreads();
        int e0 = blockIdx.x * EPB;
#pragma unroll
        for (int k = 0; k < EPB / (TPB * 4); ++k) {
            int e = e0 + k * TPB * 4 + t * 4;
            if (e + 3 < n_edges) {
                int4 d4 = *(const int4*)(dst + e);
                atomicAdd(&cnt[d4.x >> BSH], 1);
                atomicAdd(&cnt[d4.y >> BSH], 1);
                atomicAdd(&cnt[d4.z >> BSH], 1);
                atomicAdd(&cnt[d4.w >> BSH], 1);
            } else {
                int qe = min(e + 4, n_edges);
                for (int q = e; q < qe; ++q)
                    atomicAdd(&cnt[dst[q] >> BSH], 1);
            }
        }
        __syncthreads();
        for (int b = t; b < NB; b += TPB)
            raw[(size_t)blockIdx.x * NB + b] = cnt[b];
    } else {
        int n = ((int)blockIdx.x - NBLK) * TPB + t;
        if (n >= n_nodes) return;
        float x0 = x[3*n], x1 = x[3*n+1], x2 = x[3*n+2];
        float f[11];
#pragma unroll
        for (int c = 0; c < 8; ++c)
            f[c] = tanhf(b_in[c] + x0*W_in[c] + x1*W_in[8+c] + x2*W_in[16+c]);
        f[8] = x0; f[9] = x1; f[10] = x2;
        float giv[8], gjv[8];
#pragma unroll
        for (int h = 0; h < 8; ++h) {
            float vi = b1[h], vj = 0.0f;
#pragma unroll
            for (int k = 0; k < 11; ++k) {
                float wa = W1[k*8+h], wb = W1[(11+k)*8+h];
                vi += f[k] * (wa - wb);
                vj += f[k] * wb;
            }
            giv[h] = __expf(-vi); gjv[h] = __expf(-vj);
        }
        float4* gip = (float4*)(egi + (size_t)n * 8);
        gip[0] = make_float4(giv[0], giv[1], giv[2], giv[3]);
        gip[1] = make_float4(giv[4], giv[5], giv[6], giv[7]);
        __align__(16) __half hj[8];
#pragma unroll
        for (int k = 0; k < 8; ++k) hj[k] = __float2half_rn(gjv[k]);
        *(uint4*)(egjh + (size_t)n * 8) = *(const uint4*)hj;
    }
}

// ===========================================================================
// K2: per-bucket (column) exclusive scan over blocks: raw -> rel, totals
// ===========================================================================
__global__ void k_scan_cols(const int* __restrict__ raw, int* __restrict__ rel,
                            int* __restrict__ totals, int NB, int NBLK) {
    __shared__ int s[TPB];
    int b = blockIdx.x, t = threadIdx.x;
    int carry = 0;
    for (int q = 0; q < NBLK; q += TPB) {
        int blk = q + t;
        int v = (blk < NBLK) ? raw[(size_t)blk * NB + b] : 0;
        __syncthreads();
        s[t] = v; __syncthreads();
        for (int o = 1; o < TPB; o <<= 1) {
            int u = (t >= o) ? s[t - o] : 0;
            __syncthreads();
            s[t] += u;
            __syncthreads();
        }
        if (blk < NBLK) rel[(size_t)blk * NB + b] = carry + s[t] - v;
        carry += s[TPB - 1];
    }
    if (t == 0) totals[b] = carry;
}

// K2b: exclusive scan of 4-padded totals -> base (1 block, trivial)
__global__ void k_base(const int* __restrict__ totals, int* __restrict__ base,
                       int NB) {
    __shared__ int s[NBMAX];
    int t = threadIdx.x;
    int v = (t < NB) ? ((totals[t] + 3) & ~3) : 0;
    s[t] = v; __syncthreads();
    for (int o = 1; o < NBMAX; o <<= 1) {
        int u = (t >= o) ? s[t - o] : 0;
        __syncthreads();
        s[t] += u;
        __syncthreads();
    }
    if (t < NB) base[t] = s[t] - v;
}

// ===========================================================================
// K3: LDS-staged local sort + coalesced run write-out (32 KB stage).
// ===========================================================================
__launch_bounds__(TPB)
__global__ void k_scatter(const int* __restrict__ src, const int* __restrict__ dst,
                          const int* __restrict__ raw, const int* __restrict__ rel,
                          const int* __restrict__ base,
                          int* __restrict__ sorted, int n_edges, int NB) {
    __shared__ int stage[EPB];        // 32 KB
    __shared__ int cnt[NBMAX];
    __shared__ int lscan[NBMAX];
    __shared__ int gd[NBMAX];
    __shared__ int s[TPB];
    int t = threadIdx.x;

    // local exclusive scan of this block's raw counts (NB <= 256: one chunk)
    {
        int v = (t < NB) ? raw[(size_t)blockIdx.x * NB + t] : 0;
        s[t] = v; __syncthreads();
        for (int o = 1; o < TPB; o <<= 1) {
            int u = (t >= o) ? s[t - o] : 0;
            __syncthreads();
            s[t] += u;
            __syncthreads();
        }
        if (t < NB) {
            lscan[t] = s[t] - v;
            cnt[t]   = s[t] - v;
            gd[t]    = base[t] + rel[(size_t)blockIdx.x * NB + t];
        }
    }
    __syncthreads();

    int e0 = blockIdx.x * EPB;
#pragma unroll
    for (int k = 0; k < EPB / (TPB * 4); ++k) {
        int e = e0 + k * TPB * 4 + t * 4;
        if (e + 3 < n_edges) {
            int4 s4 = *(const int4*)(src + e);
            int4 d4 = *(const int4*)(dst + e);
            int p;
            p = atomicAdd(&cnt[d4.x >> BSH], 1); stage[p] = (s4.x << BSH) | (d4.x & (BW-1));
            p = atomicAdd(&cnt[d4.y >> BSH], 1); stage[p] = (s4.y << BSH) | (d4.y & (BW-1));
            p = atomicAdd(&cnt[d4.z >> BSH], 1); stage[p] = (s4.z << BSH) | (d4.z & (BW-1));
            p = atomicAdd(&cnt[d4.w >> BSH], 1); stage[p] = (s4.w << BSH) | (d4.w & (BW-1));
        } else {
            int qe = min(e + 4, n_edges);
            for (int q = e; q < qe; ++q) {
                int d = dst[q];
                int p = atomicAdd(&cnt[d >> BSH], 1);
                stage[p] = (src[q] << BSH) | (d & (BW - 1));
            }
        }
    }
    __syncthreads();

    int wid = t >> 6, lane = t & 63;
    for (int b = wid; b < NB; b += (TPB / 64)) {
        int ls = lscan[b];
        int le = cnt[b];
        int g0 = gd[b];
        for (int i = ls + lane; i < le; i += 64)
            sorted[g0 + (i - ls)] = stage[i];
    }
}

// ===========================================================================
// K4: fused per-bucket-slice MLP + reduction.
//   NEW: bucket's egi window (16 KB) staged in LDS -> only gjh gathers
//   remain as VMEM latency. Fixed-point int LDS atomics, int part output.
//   LDS/block = 16 + 4 KB = 20 KB -> still thread-cap-bound 8 blocks/CU.
// ===========================================================================
__launch_bounds__(TPB, 4)
__global__ void k_bucket(const int* __restrict__ sorted, const int* __restrict__ base,
                         const int* __restrict__ totals,
                         const float* __restrict__ egi, const __half* __restrict__ egjh,
                         const float* __restrict__ W2, const float* __restrict__ b2,
                         const float* __restrict__ W_e,
                         int* __restrict__ part, int n_nodes, int NB, int NBP) {
    __shared__ float segi[BW * 8];  // 16 KB staged egi window
    __shared__ int sa[BW], sc[BW];  // 4 KB fixed-point accumulators
    int t = threadIdx.x;
    int sl = blockIdx.x / NBP;
    int b  = blockIdx.x - sl * NBP;
    if (b >= NB) return;

    int nb0 = b * BW;
    int nn = min(BW, n_nodes - nb0);
    const float4* gsrc = (const float4*)(egi + (size_t)nb0 * 8);
    for (int i = t; i < nn * 2; i += TPB) ((float4*)segi)[i] = gsrc[i];
    for (int i = t; i < BW; i += TPB) { sa[i] = 0; sc[i] = 0; }
    __syncthreads();

    int beg = base[b];
    int len = totals[b];
    int qs = (((len + S_SPLIT - 1) / S_SPLIT) + 3) & ~3;
    int s0 = beg + sl * qs;
    int s1 = min(beg + len, s0 + qs);

    for (int g = s0 + t * 4; g < s1; g += TPB * 4) {
        if (g + 4 <= s1) {
            int4 pp = *(const int4*)(sorted + g);
            int d[4]  = { pp.x & (BW-1), pp.y & (BW-1), pp.z & (BW-1), pp.w & (BW-1) };
            int sj[4] = { pp.x >> BSH,   pp.y >> BSH,   pp.z >> BSH,   pp.w >> BSH };
            float ej[4][8];
#pragma unroll
            for (int q = 0; q < 4; ++q)
                unpack8(*(const uint4*)(egjh + (size_t)sj[q] * 8), ej[q]);
            float m[4][8];
#pragma unroll
            for (int q = 0; q < 4; ++q) {
                const float4* ip = (const float4*)(&segi[d[q] * 8]);
                float4 A = ip[0], B = ip[1];
                float ei[8] = {A.x,A.y,A.z,A.w,B.x,B.y,B.z,B.w};
#pragma unroll
                for (int k = 0; k < 8; ++k)
                    m[q][k] = __builtin_amdgcn_rcpf(1.0f + ei[k] * ej[q][k]);
            }
            float pa[4] = {0,0,0,0}, pc[4] = {0,0,0,0};
#pragma unroll
            for (int h = 0; h < 8; ++h) {
                float bb = b2[h];
                float v[4] = {bb, bb, bb, bb};
#pragma unroll
                for (int k = 0; k < 8; ++k) {
                    float w = W2[k*8+h];
#pragma unroll
                    for (int q = 0; q < 4; ++q) v[q] += m[q][k] * w;
                }
                float wa = W_e[h], wc = W_e[11+h];
#pragma unroll
                for (int q = 0; q < 4; ++q) {
                    float z = sigmoidf(v[q]);
                    pa[q] += z * wa; pc[q] += z * wc;
                }
            }
#pragma unroll
            for (int q = 0; q < 4; ++q) {
                atomicAdd(&sa[d[q]], __float2int_rn(pa[q] * FXS));
                atomicAdd(&sc[d[q]], __float2int_rn(pc[q] * FXS));
            }
        } else {
            for (int e = g; e < s1; ++e) {
                int p = sorted[e];
                int dl = p & (BW - 1);
                float ej[8];
                unpack8(*(const uint4*)(egjh + (size_t)(p >> BSH) * 8), ej);
                const float4* ip = (const float4*)(&segi[dl * 8]);
                float4 A = ip[0], B = ip[1];
                float ei[8] = {A.x,A.y,A.z,A.w,B.x,B.y,B.z,B.w};
                float m[8];
#pragma unroll
                for (int k = 0; k < 8; ++k)
                    m[k] = __builtin_amdgcn_rcpf(1.0f + ei[k] * ej[k]);
                float pa = 0, pc = 0;
#pragma unroll
                for (int h = 0; h < 8; ++h) {
                    float v = b2[h];
#pragma unroll
                    for (int k = 0; k < 8; ++k) v += m[k] * W2[k*8+h];
                    float z = sigmoidf(v);
                    pa += z * W_e[h]; pc += z * W_e[11+h];
                }
                atomicAdd(&sa[dl], __float2int_rn(pa * FXS));
                atomicAdd(&sc[dl], __float2int_rn(pc * FXS));
            }
        }
    }
    __syncthreads();
    size_t row = (size_t)blockIdx.x * (2 * BW);
    for (int i = t; i < BW; i += TPB) {
        part[row + i]      = sa[i];
        part[row + BW + i] = sc[i];
    }
}

// ===========================================================================
// K5: reduce S_SPLIT int partials (exact) + x-projection -> ac[2n], ac[2n+1]
// ===========================================================================
__global__ void k_acc(const int* __restrict__ part, const float* __restrict__ x,
                      const float* __restrict__ W_e, float* __restrict__ ac,
                      int n_nodes, int NBP) {
    int n = blockIdx.x * blockDim.x + threadIdx.x;
    if (n >= n_nodes) return;
    int b = n >> BSH, r = n & (BW - 1);
    int ia = 0, ic = 0;
#pragma unroll
    for (int s = 0; s < S_SPLIT; ++s) {
        const int* pp = part + ((size_t)(s * NBP + b)) * (2 * BW);
        ia += pp[r];
        ic += pp[BW + r];
    }
    float a = (float)ia * FXSI, c = (float)ic * FXSI;
    float x0 = x[3*n], x1 = x[3*n+1], x2 = x[3*n+2];
    a += x0 * W_e[8]  + x1 * W_e[9]  + x2 * W_e[10];
    c += x0 * W_e[19] + x1 * W_e[20] + x2 * W_e[21];
    ac[2*n]     = a;
    ac[2*n + 1] = c;
}

// ===========================================================================
// K6: out[e] = sigmoid(a[src] + c[dst] + b_e), 4 edges/thread
// ===========================================================================
__global__ void k_out2(const int* __restrict__ src, const int* __restrict__ dst,
                       const float* __restrict__ ac, const float* __restrict__ b_e,
                       float* __restrict__ out, int n_edges) {
    float bb = b_e[0];
    int e = (blockIdx.x * blockDim.x + threadIdx.x) * 4;
    if (e + 3 < n_edges) {
        int4 s4 = *(const int4*)(src + e);
        int4 d4 = *(const int4*)(dst + e);
        float4 o;
        o.x = sigmoidf(ac[2*s4.x] + ac[2*d4.x + 1] + bb);
        o.y = sigmoidf(ac[2*s4.y] + ac[2*d4.y + 1] + bb);
        o.z = sigmoidf(ac[2*s4.z] + ac[2*d4.z + 1] + bb);
        o.w = sigmoidf(ac[2*s4.w] + ac[2*d4.w + 1] + bb);
        *(float4*)(out + e) = o;
    } else {
        for (int q = e; q < n_edges; ++q)
            out[q] = sigmoidf(ac[2*src[q]] + ac[2*dst[q] + 1] + bb);
    }
}

// ===========================================================================
// FALLBACK (round-1, proven) — only if NB > NBMAX or ws too small.
// ===========================================================================
__global__ void k_nodes(const float* __restrict__ x, const float* __restrict__ W_in,
                        const float* __restrict__ b_in, float* __restrict__ feat,
                        float* __restrict__ H2, int n_nodes) {
    int i = blockIdx.x * blockDim.x + threadIdx.x;
    if (i >= n_nodes) return;
    float x0 = x[3*i], x1 = x[3*i+1], x2 = x[3*i+2];
    float h[8];
#pragma unroll
    for (int c = 0; c < 8; ++c)
        h[c] = tanhf(b_in[c] + x0*W_in[c] + x1*W_in[8+c] + x2*W_in[16+c]);
    float4* fp = (float4*)(feat + (size_t)i * 12);
    fp[0] = make_float4(h[0],h[1],h[2],h[3]);
    fp[1] = make_float4(h[4],h[5],h[6],h[7]);
    fp[2] = make_float4(x0,x1,x2,0.0f);
    float4* hp = (float4*)(H2 + (size_t)i * 8);
    hp[0] = make_float4(0,0,0,0); hp[1] = make_float4(0,0,0,0);
}

__global__ void k_edges(const int* __restrict__ src, const int* __restrict__ dst,
                        const float* __restrict__ feat, const float* __restrict__ W1,
                        const float* __restrict__ b1, const float* __restrict__ W2,
                        const float* __restrict__ b2, float* __restrict__ H2,
                        int n_edges) {
    __shared__ float sW1[176], sW2[64], sb1[8], sb2[8];
    for (int t = threadIdx.x; t < 176; t += blockDim.x) sW1[t] = W1[t];
    for (int t = threadIdx.x; t < 64;  t += blockDim.x) sW2[t] = W2[t];
    if (threadIdx.x < 8) { sb1[threadIdx.x]=b1[threadIdx.x]; sb2[threadIdx.x]=b2[threadIdx.x]; }
    __syncthreads();
    int e = blockIdx.x * blockDim.x + threadIdx.x;
    if (e >= n_edges) return;
    int j = src[e], i = dst[e];
    const float4* fi = (const float4*)(feat + (size_t)i * 12);
    const float4* fj = (const float4*)(feat + (size_t)j * 12);
    float4 i0=fi[0],i1=fi[1],i2=fi[2],j0=fj[0],j1=fj[1],j2=fj[2];
    float xi[11]={i0.x,i0.y,i0.z,i0.w,i1.x,i1.y,i1.z,i1.w,i2.x,i2.y,i2.z};
    float xj[11]={j0.x,j0.y,j0.z,j0.w,j1.x,j1.y,j1.z,j1.w,j2.x,j2.y,j2.z};
    float dd[11];
#pragma unroll
    for (int k = 0; k < 11; ++k) dd[k]=xj[k]-xi[k];
    float m[8];
#pragma unroll
    for (int h = 0; h < 8; ++h) {
        float v = sb1[h];
#pragma unroll
        for (int k = 0; k < 11; ++k) v += xi[k]*sW1[k*8+h];
#pragma unroll
        for (int k = 0; k < 11; ++k) v += dd[k]*sW1[(11+k)*8+h];
        m[h] = sigmoidf(v);
    }
    float m2[8];
#pragma unroll
    for (int h = 0; h < 8; ++h) {
        float v = sb2[h];
#pragma unroll
        for (int k = 0; k < 8; ++k) v += m[k]*sW2[k*8+h];
        m2[h] = sigmoidf(v);
    }
    float* hp = H2 + (size_t)i * 8;
#pragma unroll
    for (int h = 0; h < 8; ++h) atomicAdd(hp + h, m2[h]);
}

__global__ void k_out(const int* __restrict__ src, const int* __restrict__ dst,
                      const float* __restrict__ H2, const float* __restrict__ x,
                      const float* __restrict__ W_e, const float* __restrict__ b_e,
                      float* __restrict__ out, int n_edges) {
    __shared__ float sW[22]; __shared__ float sb;
    if (threadIdx.x < 22) sW[threadIdx.x] = W_e[threadIdx.x];
    if (threadIdx.x == 0) sb = b_e[0];
    __syncthreads();
    int e = blockIdx.x * blockDim.x + threadIdx.x;
    if (e >= n_edges) return;
    int j = src[e], i = dst[e];
    const float4* hj = (const float4*)(H2 + (size_t)j * 8);
    const float4* hi = (const float4*)(H2 + (size_t)i * 8);
    float4 a0=hj[0],a1=hj[1],c0=hi[0],c1=hi[1];
    float acc = sb;
    acc += a0.x*sW[0]+a0.y*sW[1]+a0.z*sW[2]+a0.w*sW[3];
    acc += a1.x*sW[4]+a1.y*sW[5]+a1.z*sW[6]+a1.w*sW[7];
    acc += x[3*(size_t)j]*sW[8]+x[3*(size_t)j+1]*sW[9]+x[3*(size_t)j+2]*sW[10];
    acc += c0.x*sW[11]+c0.y*sW[12]+c0.z*sW[13]+c0.w*sW[14];
    acc += c1.x*sW[15]+c1.y*sW[16]+c1.z*sW[17]+c1.w*sW[18];
    acc += x[3*(size_t)i]*sW[19]+x[3*(size_t)i+1]*sW[20]+x[3*(size_t)i+2]*sW[21];
    out[e] = sigmoidf(acc);
}

// ===========================================================================
extern "C" void kernel_launch(void* const* d_in, const int* in_sizes, int n_in,
                              void* d_out, int out_size, void* d_ws, size_t ws_size,
                              hipStream_t stream) {
    const float* x    = (const float*)d_in[0];
    const int*   ei   = (const int*)d_in[1];
    const float* W_in = (const float*)d_in[2];
    const float* b_in = (const float*)d_in[3];
    const float* W1   = (const float*)d_in[4];
    const float* b1   = (const float*)d_in[5];
    const float* W2   = (const float*)d_in[6];
    const float* b2   = (const float*)d_in[7];
    const float* W_e  = (const float*)d_in[8];
    const float* b_e  = (const float*)d_in[9];

    const int n_nodes = in_sizes[0] / 3;
    const int n_edges = in_sizes[1] / 2;
    const int* src = ei;
    const int* dst = ei + n_edges;
    float* out = (float*)d_out;

    const int NB   = (n_nodes + BW - 1) >> BSH;
    const int NBP  = (NB + 7) & ~7;
    const int NBLK = (n_edges + EPB - 1) / EPB;
    const int NFB  = (n_nodes + TPB - 1) / TPB;

    size_t off = 0;
    auto carve = [&](size_t bytes) { size_t o = off; off += (bytes + 255) & ~(size_t)255; return o; };
    char* ws = (char*)d_ws;
    size_t o_egi    = carve((size_t)n_nodes * 8 * 4);
    size_t o_egjh   = carve((size_t)n_nodes * 8 * 2);
    size_t o_ac     = carve((size_t)n_nodes * 2 * 4);
    size_t o_raw    = carve((size_t)NBLK * NB * 4);
    size_t o_rel    = carve((size_t)NBLK * NB * 4);
    size_t o_totals = carve((size_t)NB * 4);
    size_t o_base   = carve(((size_t)NB + 1) * 4);
    size_t o_sorted = carve(((size_t)n_edges + 4 * NBMAX) * 4);
    size_t o_part   = carve((size_t)NBP * S_SPLIT * 2 * BW * 4);
    bool fast = (off <= ws_size) && (NB <= NBMAX);

    if (fast) {
        float*  egi    = (float*)(ws + o_egi);
        __half* egjh   = (__half*)(ws + o_egjh);
        float*  ac     = (float*)(ws + o_ac);
        int*    raw    = (int*)(ws + o_raw);
        int*    rel    = (int*)(ws + o_rel);
        int*    totals = (int*)(ws + o_totals);
        int*    base   = (int*)(ws + o_base);
        int*    sorted = (int*)(ws + o_sorted);
        int*    part   = (int*)(ws + o_part);

        k_prep     <<<NBLK + NFB, TPB, 0, stream>>>(x, W_in, b_in, W1, b1, egi, egjh,
                                                    dst, raw, n_nodes, n_edges, NB, NBLK);
        k_scan_cols<<<NB, TPB, 0, stream>>>(raw, rel, totals, NB, NBLK);
        k_base     <<<1, NBMAX, 0, stream>>>(totals, base, NB);
        k_scatter  <<<NBLK, TPB, 0, stream>>>(src, dst, raw, rel, base, sorted, n_edges, NB);
        k_bucket   <<<NBP * S_SPLIT, TPB, 0, stream>>>(sorted, base, totals, egi, egjh, W2, b2, W_e,
                                                       part, n_nodes, NB, NBP);
        k_acc      <<<(n_nodes + TPB - 1) / TPB, TPB, 0, stream>>>(part, x, W_e, ac, n_nodes, NBP);
        k_out2     <<<(n_edges / 4 + TPB - 1) / TPB + 1, TPB, 0, stream>>>(src, dst, ac, b_e, out, n_edges);
    } else {
        float* feat = (float*)d_ws;
        float* H2   = feat + (size_t)n_nodes * 12;
        k_nodes<<<(n_nodes + TPB - 1) / TPB, TPB, 0, stream>>>(x, W_in, b_in, feat, H2, n_nodes);
        k_edges<<<(n_edges + TPB - 1) / TPB, TPB, 0, stream>>>(src, dst, feat, W1, b1, W2, b2, H2, n_edges);
        k_out  <<<(n_edges + TPB - 1) / TPB, TPB, 0, stream>>>(src, dst, H2, x, W_e, b_e, out, n_edges);
    }
}